// Round 1
// 1543.242 us; speedup vs baseline: 1.2271x; 1.2271x over previous
//
#include <hip/hip_runtime.h>

typedef unsigned short u16;
typedef unsigned int   u32;

#define NB  16
#define NC  256
#define NH  80
#define NW  80
#define NHW 6400

typedef short bf16x8 __attribute__((ext_vector_type(8)));
typedef float f32x4  __attribute__((ext_vector_type(4)));

__device__ __forceinline__ float b2f(u16 u) {
  union { u32 i; float f; } c; c.i = ((u32)u) << 16; return c.f;
}
__device__ __forceinline__ u16 f2b(float f) {
  union { float f; u32 i; } c; c.f = f;
  return (u16)((c.i + 0x7FFFu + ((c.i >> 16) & 1u)) >> 16);
}
__device__ __forceinline__ void unpack8(uint4 v, float* f) {
  f[0] = b2f((u16)(v.x & 0xFFFFu)); f[1] = b2f((u16)(v.x >> 16));
  f[2] = b2f((u16)(v.y & 0xFFFFu)); f[3] = b2f((u16)(v.y >> 16));
  f[4] = b2f((u16)(v.z & 0xFFFFu)); f[5] = b2f((u16)(v.z >> 16));
  f[6] = b2f((u16)(v.w & 0xFFFFu)); f[7] = b2f((u16)(v.w >> 16));
}
// dtype-dispatched input load (flag=1: f32, flag=0: bf16)
__device__ __forceinline__ float ldx(const void* p, size_t i, int f32f) {
  return f32f ? ((const float*)p)[i] : b2f(((const u16*)p)[i]);
}

// ---- K0a: detect input dtype (1 = f32, 0 = bf16) ----
__global__ __launch_bounds__(256) void probe_dtype(const u16* __restrict__ x,
                                                   int* __restrict__ flag)
{
  __shared__ int cnt[256];
  int c = 0;
  for (int i = threadIdx.x; i < 262144; i += 256) {
    u16 u = x[i];
    if (((u >> 7) & 0xFF) == 0xFF) c++;
  }
  cnt[threadIdx.x] = c; __syncthreads();
  for (int s = 128; s > 0; s >>= 1) {
    if (threadIdx.x < s) cnt[threadIdx.x] += cnt[threadIdx.x + s];
    __syncthreads();
  }
  if (threadIdx.x == 0) *flag = (cnt[0] > 16) ? 1 : 0;
}

// ---- K0b: convert all 18 weight/bias arrays into one f32 table ----
struct CvtArgs { const void* src[18]; int cum[19]; };

__global__ __launch_bounds__(256) void cvt_weights(CvtArgs a, float* __restrict__ dst,
                                                   const int* __restrict__ flag)
{
  int f = *flag;
  int i = blockIdx.x * 256 + threadIdx.x;     // < 153600
  int s = 0;
  while (i >= a.cum[s + 1]) s++;
  int j = i - a.cum[s];
  float v = f ? ((const float*)a.src[s])[j] : b2f(((const u16*)a.src[s])[j]);
  if (!(v == v) || fabsf(v) > 1e30f) v = 0.f;  // scrub
  dst[i] = v;
}

// ---- K1: per-pixel LN stats (mean, rstd) over C ----
__global__ __launch_bounds__(256) void ln_stats(const void* __restrict__ xsrc,
    size_t xoff, const int* __restrict__ flag, float2* __restrict__ stats)
{
  int f = *flag;
  int p = blockIdx.x * 256 + threadIdx.x;      // [0, Nb*NHW)
  int bl = p / NHW, hw = p % NHW;
  size_t base = xoff + (size_t)bl * NC * NHW + hw;
  float s1 = 0.f, s2 = 0.f;
  for (int c = 0; c < NC; c++) {
    float v = ldx(xsrc, base + (size_t)c * NHW, f);
    s1 += v; s2 += v * v;
  }
  float mean = s1 * (1.f / 256.f);
  float var  = s2 * (1.f / 256.f) - mean * mean;
  stats[p] = make_float2(mean, rsqrtf(var + 1e-5f));
}

// ---- K2: fused LN + BOTH depthwise convs from one LDS-staged plane ----
__global__ __launch_bounds__(256) void dw_both(const void* __restrict__ xsrc,
    size_t xoff, const int* __restrict__ flag,
    const float2* __restrict__ stats,
    const float* __restrict__ g, const float* __restrict__ bt,
    const float* __restrict__ wx7,  const float* __restrict__ bx7,
    const float* __restrict__ wx11, const float* __restrict__ bx11,
    const float* __restrict__ wx21, const float* __restrict__ bx21,
    const float* __restrict__ wy7,  const float* __restrict__ by7,
    const float* __restrict__ wy11, const float* __restrict__ by11,
    const float* __restrict__ wy21, const float* __restrict__ by21,
    u16* __restrict__ sx, u16* __restrict__ sy)
{
  __shared__ float xn[80][81];          // normalized plane, +1 pad
  __shared__ float cwx[21], cwy[21];
  __shared__ float cbx, cby;
  int f = *flag;
  int bc = blockIdx.x;                  // bl*256 + c
  int c  = bc & 255;
  int bl = bc >> 8;
  int t = threadIdx.x;
  if (t < 21) {
    float v = wx21[c * 21 + t];
    if (t >= 5 && t <= 15) v += wx11[c * 11 + t - 5];
    if (t >= 7 && t <= 13) v += wx7[c * 7 + t - 7];
    cwx[t] = v;
  } else if (t < 42) {
    int j = t - 21;
    float v = wy21[c * 21 + j];
    if (j >= 5 && j <= 15) v += wy11[c * 11 + j - 5];
    if (j >= 7 && j <= 13) v += wy7[c * 7 + j - 7];
    cwy[j] = v;
  } else if (t == 42) { cbx = bx7[c] + bx11[c] + bx21[c]; }
  else if (t == 43)   { cby = by7[c] + by11[c] + by21[c]; }
  float cg = g[c], cbt = bt[c];
  size_t xrow = xoff + (size_t)bc * NHW;
  const float2* st = stats + (size_t)bl * NHW;
  for (int i = t; i < NHW; i += 256) {
    float v = ldx(xsrc, xrow + i, f);
    float2 s = st[i];
    xn[i / 80][i % 80] = (v - s.x) * s.y * cg + cbt;
  }
  __syncthreads();
  float bxv = cbx, byv = cby;
  size_t obase = (size_t)bc * NHW;
  for (int k = 0; k < 25; k++) {
    int p = t + 256 * k;
    int h = p / 80, w = p % 80;
    float ax = bxv, ay = byv;
    #pragma unroll
    for (int d = -10; d <= 10; d++) {
      int wp = w + d;
      if (wp >= 0 && wp < NW) ax += cwx[d + 10] * xn[h][wp];
      int hp = h + d;
      if (hp >= 0 && hp < NH) ay += cwy[d + 10] * xn[hp][w];
    }
    sx[obase + p] = f2b(ax);
    sy[obase + p] = f2b(ay);
  }
}

// ---- K3: IN-PLACE pointwise conv on a bf16 ws buffer ----
__global__ __launch_bounds__(256) void pw_inplace(const float* __restrict__ Wt,
    u16* io, const float* __restrict__ bias)
{
  __shared__ u16 Is[256][64];
  __shared__ float Ws[8][256];
  int bl = blockIdx.y;
  int p0 = blockIdx.x * 64;
  int t = threadIdx.x;
  {
    const u16* src = io + ((size_t)bl * NC + t) * NHW + p0;
    uint4* dstv = (uint4*)&Is[t][0];
    #pragma unroll
    for (int j = 0; j < 8; j++) dstv[j] = *(const uint4*)(src + j * 8);
  }
  __syncthreads();
  int to = t >> 3, tp = t & 7;
  float acc[8][8] = {};
  for (int k0 = 0; k0 < 256; k0 += 8) {
    float4 wa = *(const float4*)(Wt + (size_t)t * 256 + k0);
    float4 wb = *(const float4*)(Wt + (size_t)t * 256 + k0 + 4);
    __syncthreads();
    Ws[0][t] = wa.x; Ws[1][t] = wa.y; Ws[2][t] = wa.z; Ws[3][t] = wa.w;
    Ws[4][t] = wb.x; Ws[5][t] = wb.y; Ws[6][t] = wb.z; Ws[7][t] = wb.w;
    __syncthreads();
    #pragma unroll
    for (int kk = 0; kk < 8; kk++) {
      float4 a0 = *(float4*)&Ws[kk][to * 8];
      float4 a1 = *(float4*)&Ws[kk][to * 8 + 4];
      uint4 bv = *(uint4*)&Is[k0 + kk][tp * 8];
      float bb[8]; unpack8(bv, bb);
      float a[8] = {a0.x, a0.y, a0.z, a0.w, a1.x, a1.y, a1.z, a1.w};
      #pragma unroll
      for (int r = 0; r < 8; r++)
        #pragma unroll
        for (int s = 0; s < 8; s++)
          acc[r][s] += a[r] * bb[s];
    }
  }
  #pragma unroll
  for (int r = 0; r < 8; r++) {
    int o = to * 8 + r;
    float bv = bias[o];
    size_t idx = ((size_t)bl * NC + o) * NHW + p0 + tp * 8;
    ushort4 v0, v1;
    v0.x = f2b(acc[r][0] + bv); v0.y = f2b(acc[r][1] + bv);
    v0.z = f2b(acc[r][2] + bv); v0.w = f2b(acc[r][3] + bv);
    v1.x = f2b(acc[r][4] + bv); v1.y = f2b(acc[r][5] + bv);
    v1.z = f2b(acc[r][6] + bv); v1.w = f2b(acc[r][7] + bv);
    *(ushort4*)(io + idx)     = v0;
    *(ushort4*)(io + idx + 4) = v1;
  }
}

// ---- K8: final pointwise: Out = 2*bias + W*In + x ----
__global__ __launch_bounds__(256) void pw_final(const float* __restrict__ Wt,
    const u16* __restrict__ In, void* __restrict__ OutBase, size_t out_off,
    const float* __restrict__ bias,
    const void* __restrict__ xsrc, size_t xoff, const int* __restrict__ flag)
{
  __shared__ u16 Is[256][64];
  __shared__ float Ws[8][256];
  int f = *flag;
  int bl = blockIdx.y;
  int p0 = blockIdx.x * 64;
  int t = threadIdx.x;
  {
    const u16* src = In + ((size_t)bl * NC + t) * NHW + p0;
    uint4* dstv = (uint4*)&Is[t][0];
    #pragma unroll
    for (int j = 0; j < 8; j++) dstv[j] = *(const uint4*)(src + j * 8);
  }
  __syncthreads();
  int to = t >> 3, tp = t & 7;
  float acc[8][8] = {};
  for (int k0 = 0; k0 < 256; k0 += 8) {
    float4 wa = *(const float4*)(Wt + (size_t)t * 256 + k0);
    float4 wb = *(const float4*)(Wt + (size_t)t * 256 + k0 + 4);
    __syncthreads();
    Ws[0][t] = wa.x; Ws[1][t] = wa.y; Ws[2][t] = wa.z; Ws[3][t] = wa.w;
    Ws[4][t] = wb.x; Ws[5][t] = wb.y; Ws[6][t] = wb.z; Ws[7][t] = wb.w;
    __syncthreads();
    #pragma unroll
    for (int kk = 0; kk < 8; kk++) {
      float4 a0 = *(float4*)&Ws[kk][to * 8];
      float4 a1 = *(float4*)&Ws[kk][to * 8 + 4];
      uint4 bv = *(uint4*)&Is[k0 + kk][tp * 8];
      float bb[8]; unpack8(bv, bb);
      float a[8] = {a0.x, a0.y, a0.z, a0.w, a1.x, a1.y, a1.z, a1.w};
      #pragma unroll
      for (int r = 0; r < 8; r++)
        #pragma unroll
        for (int s = 0; s < 8; s++)
          acc[r][s] += a[r] * bb[s];
    }
  }
  #pragma unroll
  for (int r = 0; r < 8; r++) {
    int o = to * 8 + r;
    float bv = 2.f * bias[o];
    size_t idx = ((size_t)bl * NC + o) * NHW + p0 + tp * 8;
    #pragma unroll
    for (int s = 0; s < 8; s++) {
      float v = acc[r][s] + bv + ldx(xsrc, xoff + idx + s, f);
      if (f) ((float*)OutBase)[out_off + idx + s] = v;
      else   ((u16*)OutBase)[out_off + idx + s]   = f2b(v);
    }
  }
}

// ---- K4: per-(bl,c) row/col sum of squares ----
__global__ __launch_bounds__(256) void rowcol_sumsq(const u16* __restrict__ fx, const u16* __restrict__ fy,
    float* __restrict__ rs_fx, float* __restrict__ rs_fy,
    float* __restrict__ cs_fx, float* __restrict__ cs_fy)
{
  __shared__ float tile[80][81];
  int bc = blockIdx.x; int ten = blockIdx.y;
  const u16* src = (ten ? fy : fx) + (size_t)bc * NHW;
  int t = threadIdx.x;
  for (int i = t; i < NHW; i += 256) {
    float v = b2f(src[i]);
    tile[i / 80][i % 80] = v * v;
  }
  __syncthreads();
  if (t < 80) {
    float s = 0.f;
    #pragma unroll
    for (int k = 0; k < 80; k++) s += tile[t][k];
    (ten ? rs_fy : rs_fx)[bc * 80 + t] = s;
  } else if (t < 160) {
    int w = t - 80; float s = 0.f;
    #pragma unroll
    for (int h = 0; h < 80; h++) s += tile[h][w];
    (ten ? cs_fy : cs_fx)[bc * 80 + w] = s;
  }
}

// ---- K5: combine over ci -> inverse norms ----
__global__ __launch_bounds__(256) void norm_combine(const float* __restrict__ rs_fx,
    const float* __restrict__ rs_fy, const float* __restrict__ cs_fx,
    const float* __restrict__ cs_fy, float* __restrict__ invn, int Nb)
{
  int t = blockIdx.x * 256 + threadIdx.x;   // 4*Nb*640 total
  int blk = Nb * 640;
  int side = t / blk, r = t % blk;
  int b = r / 640, rem = r % 640, hd = rem / 80, row = rem % 80;
  const float* src = (side == 0) ? rs_fy : (side == 1) ? rs_fx : (side == 2) ? cs_fx : cs_fy;
  size_t base = (size_t)(b * 256 + hd * 32) * 80 + row;
  float s = 0.f;
  #pragma unroll
  for (int ci = 0; ci < 32; ci++) s += src[base + ci * 80];
  invn[t] = 1.f / fmaxf(sqrtf(s), 1e-12f);
}

// ---- K-T: per-plane 80x80 bf16 transpose: [c][h][w] -> [c][w][h].
// Gives axis-1 gram and apply_hw their k-contiguous MFMA operands. ----
__global__ __launch_bounds__(256) void transpose_hw(const u16* __restrict__ fx,
    const u16* __restrict__ fy, u16* __restrict__ fxT, u16* __restrict__ fyT)
{
  __shared__ u16 tile[80][81];
  size_t pl = blockIdx.x;
  const u16* src = (blockIdx.y ? fy : fx) + pl * NHW;
  u16*       dst = (blockIdx.y ? fyT : fxT) + pl * NHW;
  int t = threadIdx.x;
  for (int i = t; i < NHW; i += 256) tile[i / 80][i % 80] = src[i];
  __syncthreads();
  for (int i = t; i < NHW; i += 256) dst[i] = tile[i % 80][i / 80];
}

// ---- MFMA helpers for 80x80 Gram-style tiles.
// Tiles tt = m*5+n over the 5x5 grid of 16x16 output tiles; waves own static
// contiguous ranges {0..6},{7..12},{13..18},{19..24} (2 m-values each).
// K is consumed in 3 chunks of 32 (last zero-padded: k=80..95 -> A-frag 0).
// A and B fragments use the SAME lane->k convention (k = 32*ch + 8*(l>>4)+j),
// so any internal k-permutation of the MFMA cancels; C/D layout per m89:
// col = lane&15, row = (lane>>4)*4 + reg. ----
template<int T0, int NT>
__device__ __forceinline__ void gram_wave(const u16* pa, const u16* pb,
                                          int lg, int lr, f32x4* acc)
{
  constexpr int MLO = T0 / 5;
  #pragma unroll
  for (int ch = 0; ch < 3; ch++) {
    bool tz = (ch == 2) && (lg >= 2);
    int kk = ch * 32 + 8 * lg;
    if (tz) kk = 0;
    bf16x8 af[2], bf[5];
    #pragma unroll
    for (int m = 0; m < 2; m++)
      af[m] = *(const bf16x8*)(pa + ((MLO + m) * 16 + lr) * 80 + kk);
    #pragma unroll
    for (int n = 0; n < 5; n++)
      bf[n] = *(const bf16x8*)(pb + (n * 16 + lr) * 80 + kk);
    if (tz) {
      bf16x8 z = {0, 0, 0, 0, 0, 0, 0, 0};
      af[0] = z; af[1] = z;
    }
    #pragma unroll
    for (int j = 0; j < NT; j++) {
      acc[j] = __builtin_amdgcn_mfma_f32_16x16x32_bf16(
          af[(T0 + j) / 5 - MLO], bf[(T0 + j) % 5], acc[j], 0, 0, 0);
    }
  }
}

template<int T0, int NT>
__device__ __forceinline__ void gram_all(const u16* Ab, const u16* Bb,
                                         int lg, int lr, f32x4* acc)
{
  for (int ci = 0; ci < 32; ci++)
    gram_wave<T0, NT>(Ab + (size_t)ci * NHW, Bb + (size_t)ci * NHW, lg, lr, acc);
}

// ---- K6: MFMA Gram (sum over 32 ci) + cosine scale + softmax -> Sbuf ----
__global__ __launch_bounds__(256) void gram_softmax_mfma(const u16* __restrict__ fx,
    const u16* __restrict__ fy, const u16* __restrict__ fxT, const u16* __restrict__ fyT,
    const float* __restrict__ invn, u16* __restrict__ Sbuf, int Nb)
{
  __shared__ float At[80][81];
  int hd = blockIdx.x, b = blockIdx.y, axis = blockIdx.z;
  size_t sl0 = (size_t)(b * 256 + hd * 32) * NHW;
  // axis0 (H attn): q rows = fy planes [h][w], k rows = fx planes   (contract w)
  // axis1 (W attn): q rows = fxT planes [w][h], k rows = fyT planes (contract h)
  const u16* Ab = (axis ? fxT : fy) + sl0;
  const u16* Bb = (axis ? fyT : fx) + sl0;
  int t = threadIdx.x, lane = t & 63, wid = t >> 6;
  int lg = lane >> 4, lr = lane & 15;
  f32x4 acc0 = {0.f, 0.f, 0.f, 0.f};
  f32x4 acc[7];
  #pragma unroll
  for (int j = 0; j < 7; j++) acc[j] = acc0;
  if      (wid == 0) gram_all<0, 7>(Ab, Bb, lg, lr, acc);
  else if (wid == 1) gram_all<7, 6>(Ab, Bb, lg, lr, acc);
  else if (wid == 2) gram_all<13, 6>(Ab, Bb, lg, lr, acc);
  else               gram_all<19, 6>(Ab, Bb, lg, lr, acc);
  int blk = Nb * 640;
  int rowbase = (b * 8 + hd) * 80;
  const float* invq = invn + (axis ? 2 * blk : 0)   + rowbase;
  const float* invk = invn + (axis ? 3 * blk : blk) + rowbase;
  int t0  = wid ? 6 * wid + 1 : 0;
  int cnt = wid ? 6 : 7;
  #pragma unroll
  for (int j = 0; j < 7; j++) {
    if (j < cnt) {
      int tt = t0 + j, m = tt / 5, n = tt % 5;
      int col = n * 16 + lr;
      float ik = invk[col];
      #pragma unroll
      for (int r = 0; r < 4; r++) {
        int row = m * 16 + 4 * lg + r;
        float gv = acc[j][r] * invq[row] * ik;
        At[row][col] = fminf(fmaxf(gv, -8.f), 8.f);  // |cos|<=1; NaN->-8
      }
    }
  }
  __syncthreads();
  u16* Sg = Sbuf + ((size_t)(axis * Nb * 8 + b * 8 + hd)) * NHW;
  if (t < 80) {
    float mx = -1e30f;
    for (int j = 0; j < 80; j++) mx = fmaxf(mx, At[t][j]);
    float s = 0.f;
    for (int j = 0; j < 80; j++) s += __expf(At[t][j] - mx);
    float inv = 1.f / s;
    for (int j = 0; j < 80; j++) Sg[t * 80 + j] = f2b(__expf(At[t][j] - mx) * inv);
  }
}

// ---- K7: MFMA fused H+W attention apply, IN PLACE over fx slice.
// acc[h][w] = sum_k SH[h][k]*fx[k][w]  (A=SH rows, B=fxT rows)
//           + sum_k fy[h][k]*SW[w][k]  (A=fy rows, B=SW rows)  ----
template<int T0, int NT>
__device__ __forceinline__ void apply_wave(const u16* SH, const u16* fxT,
    const u16* fyP, const u16* SW, int lg, int lr, f32x4* acc)
{
  constexpr int MLO = T0 / 5;
  for (int ch = 0; ch < 3; ch++) {
    bool tz = (ch == 2) && (lg >= 2);
    int kk = ch * 32 + 8 * lg;
    if (tz) kk = 0;
    bf16x8 a1[2], a2[2], b1[5], b2[5];
    #pragma unroll
    for (int m = 0; m < 2; m++) {
      a1[m] = *(const bf16x8*)(SH  + ((MLO + m) * 16 + lr) * 80 + kk);
      a2[m] = *(const bf16x8*)(fyP + ((MLO + m) * 16 + lr) * 80 + kk);
    }
    #pragma unroll
    for (int n = 0; n < 5; n++) {
      b1[n] = *(const bf16x8*)(fxT + (n * 16 + lr) * 80 + kk);
      b2[n] = *(const bf16x8*)(SW  + (n * 16 + lr) * 80 + kk);
    }
    if (tz) {
      bf16x8 z = {0, 0, 0, 0, 0, 0, 0, 0};
      a1[0] = z; a1[1] = z; a2[0] = z; a2[1] = z;
    }
    #pragma unroll
    for (int j = 0; j < NT; j++) {
      acc[j] = __builtin_amdgcn_mfma_f32_16x16x32_bf16(
          a1[(T0 + j) / 5 - MLO], b1[(T0 + j) % 5], acc[j], 0, 0, 0);
      acc[j] = __builtin_amdgcn_mfma_f32_16x16x32_bf16(
          a2[(T0 + j) / 5 - MLO], b2[(T0 + j) % 5], acc[j], 0, 0, 0);
    }
  }
}

__global__ __launch_bounds__(256, 2) void apply_hw_mfma(const u16* __restrict__ fy_g,
    const u16* __restrict__ fxT_g, const u16* __restrict__ Sbuf,
    const float* __restrict__ invn, u16* fx_io, int Nb)
{
  int ci = blockIdx.x, hd = blockIdx.y, b = blockIdx.z;
  size_t off = (size_t)(b * 256 + hd * 32 + ci) * NHW;
  const u16* SgH = Sbuf + (size_t)(b * 8 + hd) * NHW;
  const u16* SgW = Sbuf + ((size_t)(Nb * 8) + b * 8 + hd) * NHW;
  const u16* fyP = fy_g + off;
  const u16* fxT = fxT_g + off;
  int t = threadIdx.x, lane = t & 63, wid = t >> 6;
  int lg = lane >> 4, lr = lane & 15;
  f32x4 acc0 = {0.f, 0.f, 0.f, 0.f};
  f32x4 acc[7];
  #pragma unroll
  for (int j = 0; j < 7; j++) acc[j] = acc0;
  if      (wid == 0) apply_wave<0, 7>(SgH, fxT, fyP, SgW, lg, lr, acc);
  else if (wid == 1) apply_wave<7, 6>(SgH, fxT, fyP, SgW, lg, lr, acc);
  else if (wid == 2) apply_wave<13, 6>(SgH, fxT, fyP, SgW, lg, lr, acc);
  else               apply_wave<19, 6>(SgH, fxT, fyP, SgW, lg, lr, acc);
  const float* invqH = invn + (b * 8 + hd) * 80;                 // H_fy(q)
  const float* invqW = invn + 2 * Nb * 640 + (b * 8 + hd) * 80;  // W_fx(q)
  int t0  = wid ? 6 * wid + 1 : 0;
  int cnt = wid ? 6 : 7;
  #pragma unroll
  for (int j = 0; j < 7; j++) {
    if (j < cnt) {
      int tt = t0 + j, m = tt / 5, n = tt % 5;
      int col = n * 16 + lr;
      float ivW = invqW[col];
      #pragma unroll
      for (int r = 0; r < 4; r++) {
        int row = m * 16 + 4 * lg + r;
        size_t ix = off + row * 80 + col;
        float v = acc[j][r] + b2f(fy_g[ix]) * invqH[row] + b2f(fx_io[ix]) * ivW;
        fx_io[ix] = f2b(v);
      }
    }
  }
}

extern "C" void kernel_launch(void* const* d_in, const int* in_sizes, int n_in,
                              void* d_out, int out_size, void* d_ws, size_t ws_size,
                              hipStream_t stream) {
  // Weight conversion table: d_in[1..18] in setup_inputs order.
  const int wsz[18] = {256, 256, 65536, 256, 65536, 256,
                       1792, 256, 2816, 256, 5376, 256,
                       1792, 256, 2816, 256, 5376, 256};
  CvtArgs ca;
  int cum = 0;
  for (int i = 0; i < 18; i++) { ca.src[i] = d_in[i + 1]; ca.cum[i] = cum; cum += wsz[i]; }
  ca.cum[18] = cum;   // 153600

  // ws layout: flag(16) | wbuf(614400) | per-chunk (Nb * 13,701,120).
  int Nb = 1;
  for (int cand = 16; cand >= 1; cand >>= 1) {
    size_t need = (size_t)cand * 13701120 + 614416;
    if (need <= ws_size) { Nb = cand; break; }
  }
  char* p = (char*)d_ws;
  int*    flag  = (int*)p;    p += 16;
  float*  wbuf  = (float*)p;  p += 614400;
  u16*    fxbuf = (u16*)p;    p += (size_t)Nb * 3276800;
  u16*    fybuf = (u16*)p;    p += (size_t)Nb * 3276800;
  u16*    fxT   = (u16*)p;    p += (size_t)Nb * 3276800;
  u16*    fyT   = (u16*)p;    p += (size_t)Nb * 3276800;
  float2* stats = (float2*)p; p += (size_t)Nb * 51200;
  float*  rs_fx = (float*)p;  p += (size_t)Nb * 81920;
  float*  rs_fy = (float*)p;  p += (size_t)Nb * 81920;
  float*  cs_fx = (float*)p;  p += (size_t)Nb * 81920;
  float*  cs_fy = (float*)p;  p += (size_t)Nb * 81920;
  float*  invn  = (float*)p;  p += (size_t)Nb * 10240;
  u16*    Sbuf  = (u16*)p;

  // f32 weight views
  float* ln_g = wbuf + ca.cum[0];  float* ln_b = wbuf + ca.cum[1];
  float* w_in = wbuf + ca.cum[2];  float* b_in = wbuf + ca.cum[3];
  float* w_out= wbuf + ca.cum[4];  float* b_out= wbuf + ca.cum[5];
  float* wx7  = wbuf + ca.cum[6];  float* bx7  = wbuf + ca.cum[7];
  float* wx11 = wbuf + ca.cum[8];  float* bx11 = wbuf + ca.cum[9];
  float* wx21 = wbuf + ca.cum[10]; float* bx21 = wbuf + ca.cum[11];
  float* wy7  = wbuf + ca.cum[12]; float* by7  = wbuf + ca.cum[13];
  float* wy11 = wbuf + ca.cum[14]; float* by11 = wbuf + ca.cum[15];
  float* wy21 = wbuf + ca.cum[16]; float* by21 = wbuf + ca.cum[17];

  probe_dtype<<<dim3(1), dim3(256), 0, stream>>>((const u16*)d_in[0], flag);
  cvt_weights<<<dim3(600), dim3(256), 0, stream>>>(ca, wbuf, flag);

  for (int b0 = 0; b0 < NB; b0 += Nb) {
    size_t xoff = (size_t)b0 * NC * NHW;   // element offset of chunk in x / out

    ln_stats<<<dim3(Nb * 25), dim3(256), 0, stream>>>(d_in[0], xoff, flag, stats);
    dw_both<<<dim3(Nb * 256), dim3(256), 0, stream>>>(d_in[0], xoff, flag, stats,
        ln_g, ln_b, wx7, bx7, wx11, bx11, wx21, bx21,
        wy7, by7, wy11, by11, wy21, by21, fxbuf, fybuf);
    pw_inplace<<<dim3(100, Nb), dim3(256), 0, stream>>>(w_in, fxbuf, b_in);
    pw_inplace<<<dim3(100, Nb), dim3(256), 0, stream>>>(w_in, fybuf, b_in);
    transpose_hw<<<dim3(Nb * 256, 2), dim3(256), 0, stream>>>(fxbuf, fybuf, fxT, fyT);
    rowcol_sumsq<<<dim3(Nb * 256, 2), dim3(256), 0, stream>>>(fxbuf, fybuf, rs_fx, rs_fy, cs_fx, cs_fy);
    norm_combine<<<dim3(10 * Nb), dim3(256), 0, stream>>>(rs_fx, rs_fy, cs_fx, cs_fy, invn, Nb);
    gram_softmax_mfma<<<dim3(8, Nb, 2), dim3(256), 0, stream>>>(fxbuf, fybuf, fxT, fyT, invn, Sbuf, Nb);
    apply_hw_mfma<<<dim3(32, 8, Nb), dim3(256), 0, stream>>>(fybuf, fxT, Sbuf, invn, fxbuf, Nb);
    pw_final<<<dim3(100, Nb), dim3(256), 0, stream>>>(w_out, fxbuf, d_out, xoff, b_out,
                                                      d_in[0], xoff, flag);
  }
  (void)in_sizes; (void)n_in; (void)out_size;
}

// Round 2
// 1185.582 us; speedup vs baseline: 1.5972x; 1.3017x over previous
//
#include <hip/hip_runtime.h>

typedef unsigned short u16;
typedef unsigned int   u32;

#define NB  16
#define NC  256
#define NH  80
#define NW  80
#define NHW 6400

typedef short bf16x8 __attribute__((ext_vector_type(8)));
typedef float f32x4  __attribute__((ext_vector_type(4)));

__device__ __forceinline__ float b2f(u16 u) {
  union { u32 i; float f; } c; c.i = ((u32)u) << 16; return c.f;
}
__device__ __forceinline__ u16 f2b(float f) {
  union { float f; u32 i; } c; c.f = f;
  return (u16)((c.i + 0x7FFFu + ((c.i >> 16) & 1u)) >> 16);
}
// dtype-dispatched input load (flag=1: f32, flag=0: bf16)
__device__ __forceinline__ float ldx(const void* p, size_t i, int f32f) {
  return f32f ? ((const float*)p)[i] : b2f(((const u16*)p)[i]);
}

// ---- K0a: detect input dtype (1 = f32, 0 = bf16) ----
__global__ __launch_bounds__(256) void probe_dtype(const u16* __restrict__ x,
                                                   int* __restrict__ flag)
{
  __shared__ int cnt[256];
  int c = 0;
  for (int i = threadIdx.x; i < 262144; i += 256) {
    u16 u = x[i];
    if (((u >> 7) & 0xFF) == 0xFF) c++;
  }
  cnt[threadIdx.x] = c; __syncthreads();
  for (int s = 128; s > 0; s >>= 1) {
    if (threadIdx.x < s) cnt[threadIdx.x] += cnt[threadIdx.x + s];
    __syncthreads();
  }
  if (threadIdx.x == 0) *flag = (cnt[0] > 16) ? 1 : 0;
}

// ---- K0b: convert all 18 weight/bias arrays into one f32 table ----
struct CvtArgs { const void* src[18]; int cum[19]; };

__global__ __launch_bounds__(256) void cvt_weights(CvtArgs a, float* __restrict__ dst,
                                                   const int* __restrict__ flag)
{
  int f = *flag;
  int i = blockIdx.x * 256 + threadIdx.x;     // < 153600
  int s = 0;
  while (i >= a.cum[s + 1]) s++;
  int j = i - a.cum[s];
  float v = f ? ((const float*)a.src[s])[j] : b2f(((const u16*)a.src[s])[j]);
  if (!(v == v) || fabsf(v) > 1e30f) v = 0.f;  // scrub
  dst[i] = v;
}

// ---- K0c: split w_in / w_out into bf16 hi+lo pairs for MFMA.
// WB layout: [mat][set][256 o][256 k] u16, mat stride 131072, set stride 65536.
__global__ __launch_bounds__(256) void split_w(const float* __restrict__ w_in,
    const float* __restrict__ w_out, u16* __restrict__ WB)
{
  int i = blockIdx.x * 256 + threadIdx.x;   // < 131072
  int mat = i >> 16, idx = i & 65535;
  float v = (mat ? w_out : w_in)[idx];
  u16 hi = f2b(v);
  u16 lo = f2b(v - b2f(hi));
  WB[mat * 131072 + idx] = hi;
  WB[mat * 131072 + 65536 + idx] = lo;
}

// ---- K1: per-pixel LN stats (mean, rstd) over C ----
__global__ __launch_bounds__(256) void ln_stats(const void* __restrict__ xsrc,
    size_t xoff, const int* __restrict__ flag, float2* __restrict__ stats)
{
  int f = *flag;
  int p = blockIdx.x * 256 + threadIdx.x;      // [0, Nb*NHW)
  int bl = p / NHW, hw = p % NHW;
  size_t base = xoff + (size_t)bl * NC * NHW + hw;
  float s1 = 0.f, s2 = 0.f;
  for (int c = 0; c < NC; c++) {
    float v = ldx(xsrc, base + (size_t)c * NHW, f);
    s1 += v; s2 += v * v;
  }
  float mean = s1 * (1.f / 256.f);
  float var  = s2 * (1.f / 256.f) - mean * mean;
  stats[p] = make_float2(mean, rsqrtf(var + 1e-5f));
}

// ---- K2: fused LN + BOTH depthwise convs from one LDS-staged plane ----
__global__ __launch_bounds__(256) void dw_both(const void* __restrict__ xsrc,
    size_t xoff, const int* __restrict__ flag,
    const float2* __restrict__ stats,
    const float* __restrict__ g, const float* __restrict__ bt,
    const float* __restrict__ wx7,  const float* __restrict__ bx7,
    const float* __restrict__ wx11, const float* __restrict__ bx11,
    const float* __restrict__ wx21, const float* __restrict__ bx21,
    const float* __restrict__ wy7,  const float* __restrict__ by7,
    const float* __restrict__ wy11, const float* __restrict__ by11,
    const float* __restrict__ wy21, const float* __restrict__ by21,
    u16* __restrict__ sx, u16* __restrict__ sy)
{
  __shared__ float xn[80][81];          // normalized plane, +1 pad
  __shared__ float cwx[21], cwy[21];
  __shared__ float cbx, cby;
  int f = *flag;
  int bc = blockIdx.x;                  // bl*256 + c
  int c  = bc & 255;
  int bl = bc >> 8;
  int t = threadIdx.x;
  if (t < 21) {
    float v = wx21[c * 21 + t];
    if (t >= 5 && t <= 15) v += wx11[c * 11 + t - 5];
    if (t >= 7 && t <= 13) v += wx7[c * 7 + t - 7];
    cwx[t] = v;
  } else if (t < 42) {
    int j = t - 21;
    float v = wy21[c * 21 + j];
    if (j >= 5 && j <= 15) v += wy11[c * 11 + j - 5];
    if (j >= 7 && j <= 13) v += wy7[c * 7 + j - 7];
    cwy[j] = v;
  } else if (t == 42) { cbx = bx7[c] + bx11[c] + bx21[c]; }
  else if (t == 43)   { cby = by7[c] + by11[c] + by21[c]; }
  float cg = g[c], cbt = bt[c];
  size_t xrow = xoff + (size_t)bc * NHW;
  const float2* st = stats + (size_t)bl * NHW;
  for (int i = t; i < NHW; i += 256) {
    float v = ldx(xsrc, xrow + i, f);
    float2 s = st[i];
    xn[i / 80][i % 80] = (v - s.x) * s.y * cg + cbt;
  }
  __syncthreads();
  float bxv = cbx, byv = cby;
  size_t obase = (size_t)bc * NHW;
  for (int k = 0; k < 25; k++) {
    int p = t + 256 * k;
    int h = p / 80, w = p % 80;
    float ax = bxv, ay = byv;
    #pragma unroll
    for (int d = -10; d <= 10; d++) {
      int wp = w + d;
      if (wp >= 0 && wp < NW) ax += cwx[d + 10] * xn[h][wp];
      int hp = h + d;
      if (hp >= 0 && hp < NH) ay += cwy[d + 10] * xn[hp][w];
    }
    sx[obase + p] = f2b(ax);
    sy[obase + p] = f2b(ay);
  }
}

// ---- K3/K8: MFMA pointwise conv. C[o][p] = sum_k W[o][k]*In[k][p], W split
// into bf16 hi+lo. One block = full 256 o x 64 px strip of one batch.
// LDS: S = InT[64px][256k] (XOR-swizzled, reg-transposed staging) + W panel
// Wp[256o][8 units of 8k] per 32-k chunk. Both A and B frags use lane->k map
// k = 32*ch + 8*lg + j (same convention as gram => permutation cancels).
// FINAL=1: out = acc + 2*bias + x, dtype-dispatched; else in-place bf16 + bias.
template<int FINAL>
__global__ __launch_bounds__(256) void pw_mfma_t(const u16* __restrict__ WB,
    u16* io0, u16* io1, const float* __restrict__ bias,
    void* __restrict__ OutBase, size_t out_off,
    const void* __restrict__ xsrc, size_t xoff, const int* __restrict__ flagp)
{
  __shared__ u16 S[32768];              // 64 KB: InT = S[0:16384], Wp = S[16384:]
  u16* InT = S;
  u16* Wp  = S + 16384;
  int bl = blockIdx.y;
  int p0 = blockIdx.x * 64;
  int t  = threadIdx.x;
  int lane = t & 63, wid = t >> 6, lg = lane >> 4, lr = lane & 15;
  u16* io = (FINAL || blockIdx.z == 0) ? io0 : io1;

  // ---- stage InT with register 8x8 transpose; swizzle col8 ^= (px&7) ----
  {
    int kb = t >> 3, pb = t & 7;
    const u16* src = io + (size_t)bl * NC * NHW + p0 + pb * 8;
    u32 r[8][4];
    #pragma unroll
    for (int i = 0; i < 8; i++) {
      uint4 v = *(const uint4*)(src + (size_t)(kb * 8 + i) * NHW);
      r[i][0] = v.x; r[i][1] = v.y; r[i][2] = v.z; r[i][3] = v.w;
    }
    #pragma unroll
    for (int j = 0; j < 8; j++) {
      u32 w[4];
      #pragma unroll
      for (int m = 0; m < 4; m++) {
        u32 a = r[2 * m][j >> 1], b = r[2 * m + 1][j >> 1];
        w[m] = (j & 1) ? ((a >> 16) | (b & 0xFFFF0000u))
                       : ((a & 0xFFFFu) | (b << 16));
      }
      int p = pb * 8 + j;
      *(uint4*)&InT[p * 256 + ((kb ^ j) * 8)] = make_uint4(w[0], w[1], w[2], w[3]);
    }
  }
  __syncthreads();

  f32x4 acc[4][4];
  #pragma unroll
  for (int m = 0; m < 4; m++)
    #pragma unroll
    for (int n = 0; n < 4; n++)
      acc[m][n] = (f32x4){0.f, 0.f, 0.f, 0.f};

  for (int ch = 0; ch < 8; ch++) {
    // stage W panel (hi unit 0..3 | lo unit 4..7) for k = ch*32..+31
    #pragma unroll
    for (int rep = 0; rep < 8; rep++) {
      int o = rep * 32 + (t >> 3), sg = t & 7;
      uint4 v = *(const uint4*)(WB + (sg >> 2) * 65536 + o * 256 + ch * 32 + (sg & 3) * 8);
      *(uint4*)&Wp[o * 64 + ((sg ^ (o & 7)) * 8)] = v;
    }
    __syncthreads();
    bf16x8 bfr[4];
    #pragma unroll
    for (int n = 0; n < 4; n++) {
      int px = n * 16 + lr;
      bfr[n] = *(const bf16x8*)&InT[px * 256 + (((ch * 4 + lg) ^ (px & 7)) * 8)];
    }
    #pragma unroll
    for (int m = 0; m < 4; m++) {
      int o = (wid * 4 + m) * 16 + lr;
      bf16x8 ahi = *(const bf16x8*)&Wp[o * 64 + ((lg ^ (o & 7)) * 8)];
      bf16x8 alo = *(const bf16x8*)&Wp[o * 64 + (((4 + lg) ^ (o & 7)) * 8)];
      #pragma unroll
      for (int n = 0; n < 4; n++) {
        acc[m][n] = __builtin_amdgcn_mfma_f32_16x16x32_bf16(ahi, bfr[n], acc[m][n], 0, 0, 0);
        acc[m][n] = __builtin_amdgcn_mfma_f32_16x16x32_bf16(alo, bfr[n], acc[m][n], 0, 0, 0);
      }
    }
    __syncthreads();
  }

  // ---- epilogue via LDS round-trip for vectorized global stores ----
  if (FINAL) {
    float* Otf = (float*)S;             // [256 o][64 px] f32, swizzled
    #pragma unroll
    for (int m = 0; m < 4; m++)
      #pragma unroll
      for (int r = 0; r < 4; r++) {
        int o = (wid * 4 + m) * 16 + 4 * lg + r;
        float bv = 2.f * bias[o];
        #pragma unroll
        for (int n = 0; n < 4; n++) {
          int px = n * 16 + lr;
          Otf[o * 64 + (px ^ ((o & 7) * 8))] = acc[m][n][r] + bv;
        }
      }
    __syncthreads();
    int f = *flagp;
    size_t gbase = ((size_t)bl * NC + t) * NHW + p0;
    #pragma unroll
    for (int j2 = 0; j2 < 16; j2++) {
      float4 v = *(float4*)&Otf[t * 64 + ((j2 * 4) ^ ((t & 7) * 8))];
      size_t gi = gbase + j2 * 4;
      if (f) {
        const float* xp = (const float*)xsrc + xoff + gi;
        v.x += xp[0]; v.y += xp[1]; v.z += xp[2]; v.w += xp[3];
        *(float4*)((float*)OutBase + out_off + gi) = v;
      } else {
        ushort4 xv = *(const ushort4*)((const u16*)xsrc + xoff + gi);
        ushort4 ov;
        ov.x = f2b(v.x + b2f(xv.x)); ov.y = f2b(v.y + b2f(xv.y));
        ov.z = f2b(v.z + b2f(xv.z)); ov.w = f2b(v.w + b2f(xv.w));
        *(ushort4*)((u16*)OutBase + out_off + gi) = ov;
      }
    }
  } else {
    u16* Ot = S;                        // [256 o][64 px] u16, swizzled
    #pragma unroll
    for (int m = 0; m < 4; m++)
      #pragma unroll
      for (int r = 0; r < 4; r++) {
        int o = (wid * 4 + m) * 16 + 4 * lg + r;
        float bv = bias[o];
        #pragma unroll
        for (int n = 0; n < 4; n++) {
          int px = n * 16 + lr;
          Ot[o * 64 + (px ^ ((o & 7) * 8))] = f2b(acc[m][n][r] + bv);
        }
      }
    __syncthreads();
    u16* orow = io + ((size_t)bl * NC + t) * NHW + p0;
    #pragma unroll
    for (int j = 0; j < 8; j++) {
      uint4 v = *(uint4*)&Ot[t * 64 + ((j ^ (t & 7)) * 8)];
      *(uint4*)(orow + j * 8) = v;
    }
  }
  (void)OutBase; (void)out_off; (void)xsrc; (void)xoff; (void)flagp; (void)io1;
}

// ---- K4: per-(bl,c) row/col sum of squares ----
__global__ __launch_bounds__(256) void rowcol_sumsq(const u16* __restrict__ fx, const u16* __restrict__ fy,
    float* __restrict__ rs_fx, float* __restrict__ rs_fy,
    float* __restrict__ cs_fx, float* __restrict__ cs_fy)
{
  __shared__ float tile[80][81];
  int bc = blockIdx.x; int ten = blockIdx.y;
  const u16* src = (ten ? fy : fx) + (size_t)bc * NHW;
  int t = threadIdx.x;
  for (int i = t; i < NHW; i += 256) {
    float v = b2f(src[i]);
    tile[i / 80][i % 80] = v * v;
  }
  __syncthreads();
  if (t < 80) {
    float s = 0.f;
    #pragma unroll
    for (int k = 0; k < 80; k++) s += tile[t][k];
    (ten ? rs_fy : rs_fx)[bc * 80 + t] = s;
  } else if (t < 160) {
    int w = t - 80; float s = 0.f;
    #pragma unroll
    for (int h = 0; h < 80; h++) s += tile[h][w];
    (ten ? cs_fy : cs_fx)[bc * 80 + w] = s;
  }
}

// ---- K5: combine over ci -> inverse norms ----
__global__ __launch_bounds__(256) void norm_combine(const float* __restrict__ rs_fx,
    const float* __restrict__ rs_fy, const float* __restrict__ cs_fx,
    const float* __restrict__ cs_fy, float* __restrict__ invn, int Nb)
{
  int t = blockIdx.x * 256 + threadIdx.x;   // 4*Nb*640 total
  int blk = Nb * 640;
  int side = t / blk, r = t % blk;
  int b = r / 640, rem = r % 640, hd = rem / 80, row = rem % 80;
  const float* src = (side == 0) ? rs_fy : (side == 1) ? rs_fx : (side == 2) ? cs_fx : cs_fy;
  size_t base = (size_t)(b * 256 + hd * 32) * 80 + row;
  float s = 0.f;
  #pragma unroll
  for (int ci = 0; ci < 32; ci++) s += src[base + ci * 80];
  invn[t] = 1.f / fmaxf(sqrtf(s), 1e-12f);
}

// ---- K-T: per-plane 80x80 bf16 transpose: [c][h][w] -> [c][w][h] ----
__global__ __launch_bounds__(256) void transpose_hw(const u16* __restrict__ fx,
    const u16* __restrict__ fy, u16* __restrict__ fxT, u16* __restrict__ fyT)
{
  __shared__ u16 tile[80][81];
  size_t pl = blockIdx.x;
  const u16* src = (blockIdx.y ? fy : fx) + pl * NHW;
  u16*       dst = (blockIdx.y ? fyT : fxT) + pl * NHW;
  int t = threadIdx.x;
  for (int i = t; i < NHW; i += 256) tile[i / 80][i % 80] = src[i];
  __syncthreads();
  for (int i = t; i < NHW; i += 256) dst[i] = tile[i % 80][i / 80];
}

// ---- MFMA helpers for 80x80 Gram-style tiles ----
template<int T0, int NT>
__device__ __forceinline__ void gram_wave(const u16* pa, const u16* pb,
                                          int lg, int lr, f32x4* acc)
{
  constexpr int MLO = T0 / 5;
  #pragma unroll
  for (int ch = 0; ch < 3; ch++) {
    bool tz = (ch == 2) && (lg >= 2);
    int kk = ch * 32 + 8 * lg;
    if (tz) kk = 0;
    bf16x8 af[2], bf[5];
    #pragma unroll
    for (int m = 0; m < 2; m++)
      af[m] = *(const bf16x8*)(pa + ((MLO + m) * 16 + lr) * 80 + kk);
    #pragma unroll
    for (int n = 0; n < 5; n++)
      bf[n] = *(const bf16x8*)(pb + (n * 16 + lr) * 80 + kk);
    if (tz) {
      bf16x8 z = {0, 0, 0, 0, 0, 0, 0, 0};
      af[0] = z; af[1] = z;
    }
    #pragma unroll
    for (int j = 0; j < NT; j++) {
      acc[j] = __builtin_amdgcn_mfma_f32_16x16x32_bf16(
          af[(T0 + j) / 5 - MLO], bf[(T0 + j) % 5], acc[j], 0, 0, 0);
    }
  }
}

template<int T0, int NT>
__device__ __forceinline__ void gram_all(const u16* Ab, const u16* Bb,
                                         int lg, int lr, f32x4* acc)
{
  for (int ci = 0; ci < 32; ci++)
    gram_wave<T0, NT>(Ab + (size_t)ci * NHW, Bb + (size_t)ci * NHW, lg, lr, acc);
}

// ---- K6: MFMA Gram (sum over 32 ci) + cosine scale + softmax -> Sbuf ----
__global__ __launch_bounds__(256) void gram_softmax_mfma(const u16* __restrict__ fx,
    const u16* __restrict__ fy, const u16* __restrict__ fxT, const u16* __restrict__ fyT,
    const float* __restrict__ invn, u16* __restrict__ Sbuf, int Nb)
{
  __shared__ float At[80][81];
  int hd = blockIdx.x, b = blockIdx.y, axis = blockIdx.z;
  size_t sl0 = (size_t)(b * 256 + hd * 32) * NHW;
  const u16* Ab = (axis ? fxT : fy) + sl0;
  const u16* Bb = (axis ? fyT : fx) + sl0;
  int t = threadIdx.x, lane = t & 63, wid = t >> 6;
  int lg = lane >> 4, lr = lane & 15;
  f32x4 acc0 = {0.f, 0.f, 0.f, 0.f};
  f32x4 acc[7];
  #pragma unroll
  for (int j = 0; j < 7; j++) acc[j] = acc0;
  if      (wid == 0) gram_all<0, 7>(Ab, Bb, lg, lr, acc);
  else if (wid == 1) gram_all<7, 6>(Ab, Bb, lg, lr, acc);
  else if (wid == 2) gram_all<13, 6>(Ab, Bb, lg, lr, acc);
  else               gram_all<19, 6>(Ab, Bb, lg, lr, acc);
  int blk = Nb * 640;
  int rowbase = (b * 8 + hd) * 80;
  const float* invq = invn + (axis ? 2 * blk : 0)   + rowbase;
  const float* invk = invn + (axis ? 3 * blk : blk) + rowbase;
  int t0  = wid ? 6 * wid + 1 : 0;
  int cnt = wid ? 6 : 7;
  #pragma unroll
  for (int j = 0; j < 7; j++) {
    if (j < cnt) {
      int tt = t0 + j, m = tt / 5, n = tt % 5;
      int col = n * 16 + lr;
      float ik = invk[col];
      #pragma unroll
      for (int r = 0; r < 4; r++) {
        int row = m * 16 + 4 * lg + r;
        float gv = acc[j][r] * invq[row] * ik;
        At[row][col] = fminf(fmaxf(gv, -8.f), 8.f);  // |cos|<=1; NaN->-8
      }
    }
  }
  __syncthreads();
  u16* Sg = Sbuf + ((size_t)(axis * Nb * 8 + b * 8 + hd)) * NHW;
  if (t < 80) {
    float mx = -1e30f;
    for (int j = 0; j < 80; j++) mx = fmaxf(mx, At[t][j]);
    float s = 0.f;
    for (int j = 0; j < 80; j++) s += __expf(At[t][j] - mx);
    float inv = 1.f / s;
    for (int j = 0; j < 80; j++) Sg[t * 80 + j] = f2b(__expf(At[t][j] - mx) * inv);
  }
}

// ---- K7: MFMA fused H+W attention apply, IN PLACE over fx slice ----
template<int T0, int NT>
__device__ __forceinline__ void apply_wave(const u16* SH, const u16* fxT,
    const u16* fyP, const u16* SW, int lg, int lr, f32x4* acc)
{
  constexpr int MLO = T0 / 5;
  for (int ch = 0; ch < 3; ch++) {
    bool tz = (ch == 2) && (lg >= 2);
    int kk = ch * 32 + 8 * lg;
    if (tz) kk = 0;
    bf16x8 a1[2], a2[2], b1[5], b2[5];
    #pragma unroll
    for (int m = 0; m < 2; m++) {
      a1[m] = *(const bf16x8*)(SH  + ((MLO + m) * 16 + lr) * 80 + kk);
      a2[m] = *(const bf16x8*)(fyP + ((MLO + m) * 16 + lr) * 80 + kk);
    }
    #pragma unroll
    for (int n = 0; n < 5; n++) {
      b1[n] = *(const bf16x8*)(fxT + (n * 16 + lr) * 80 + kk);
      b2[n] = *(const bf16x8*)(SW  + (n * 16 + lr) * 80 + kk);
    }
    if (tz) {
      bf16x8 z = {0, 0, 0, 0, 0, 0, 0, 0};
      a1[0] = z; a1[1] = z; a2[0] = z; a2[1] = z;
    }
    #pragma unroll
    for (int j = 0; j < NT; j++) {
      acc[j] = __builtin_amdgcn_mfma_f32_16x16x32_bf16(
          a1[(T0 + j) / 5 - MLO], b1[(T0 + j) % 5], acc[j], 0, 0, 0);
      acc[j] = __builtin_amdgcn_mfma_f32_16x16x32_bf16(
          a2[(T0 + j) / 5 - MLO], b2[(T0 + j) % 5], acc[j], 0, 0, 0);
    }
  }
}

__global__ __launch_bounds__(256, 2) void apply_hw_mfma(const u16* __restrict__ fy_g,
    const u16* __restrict__ fxT_g, const u16* __restrict__ Sbuf,
    const float* __restrict__ invn, u16* fx_io, int Nb)
{
  int ci = blockIdx.x, hd = blockIdx.y, b = blockIdx.z;
  size_t off = (size_t)(b * 256 + hd * 32 + ci) * NHW;
  const u16* SgH = Sbuf + (size_t)(b * 8 + hd) * NHW;
  const u16* SgW = Sbuf + ((size_t)(Nb * 8) + b * 8 + hd) * NHW;
  const u16* fyP = fy_g + off;
  const u16* fxT = fxT_g + off;
  int t = threadIdx.x, lane = t & 63, wid = t >> 6;
  int lg = lane >> 4, lr = lane & 15;
  f32x4 acc0 = {0.f, 0.f, 0.f, 0.f};
  f32x4 acc[7];
  #pragma unroll
  for (int j = 0; j < 7; j++) acc[j] = acc0;
  if      (wid == 0) apply_wave<0, 7>(SgH, fxT, fyP, SgW, lg, lr, acc);
  else if (wid == 1) apply_wave<7, 6>(SgH, fxT, fyP, SgW, lg, lr, acc);
  else if (wid == 2) apply_wave<13, 6>(SgH, fxT, fyP, SgW, lg, lr, acc);
  else               apply_wave<19, 6>(SgH, fxT, fyP, SgW, lg, lr, acc);
  const float* invqH = invn + (b * 8 + hd) * 80;                 // H_fy(q)
  const float* invqW = invn + 2 * Nb * 640 + (b * 8 + hd) * 80;  // W_fx(q)
  int t0  = wid ? 6 * wid + 1 : 0;
  int cnt = wid ? 6 : 7;
  #pragma unroll
  for (int j = 0; j < 7; j++) {
    if (j < cnt) {
      int tt = t0 + j, m = tt / 5, n = tt % 5;
      int col = n * 16 + lr;
      float ivW = invqW[col];
      #pragma unroll
      for (int r = 0; r < 4; r++) {
        int row = m * 16 + 4 * lg + r;
        size_t ix = off + row * 80 + col;
        float v = acc[j][r] + b2f(fy_g[ix]) * invqH[row] + b2f(fx_io[ix]) * ivW;
        fx_io[ix] = f2b(v);
      }
    }
  }
}

extern "C" void kernel_launch(void* const* d_in, const int* in_sizes, int n_in,
                              void* d_out, int out_size, void* d_ws, size_t ws_size,
                              hipStream_t stream) {
  // Weight conversion table: d_in[1..18] in setup_inputs order.
  const int wsz[18] = {256, 256, 65536, 256, 65536, 256,
                       1792, 256, 2816, 256, 5376, 256,
                       1792, 256, 2816, 256, 5376, 256};
  CvtArgs ca;
  int cum = 0;
  for (int i = 0; i < 18; i++) { ca.src[i] = d_in[i + 1]; ca.cum[i] = cum; cum += wsz[i]; }
  ca.cum[18] = cum;   // 153600

  // ws layout: flag(16) | wbuf(614400) | wsplit(524288) | per-chunk buffers.
  int Nb = 1;
  for (int cand = 16; cand >= 1; cand >>= 1) {
    size_t need = (size_t)cand * 13701120 + 614416 + 524288;
    if (need <= ws_size) { Nb = cand; break; }
  }
  char* p = (char*)d_ws;
  int*    flag  = (int*)p;    p += 16;
  float*  wbuf  = (float*)p;  p += 614400;
  u16*    wsplit= (u16*)p;    p += 524288;     // [2 mat][2 set][256][256] bf16
  u16*    fxbuf = (u16*)p;    p += (size_t)Nb * 3276800;
  u16*    fybuf = (u16*)p;    p += (size_t)Nb * 3276800;
  u16*    fxT   = (u16*)p;    p += (size_t)Nb * 3276800;
  u16*    fyT   = (u16*)p;    p += (size_t)Nb * 3276800;
  float2* stats = (float2*)p; p += (size_t)Nb * 51200;
  float*  rs_fx = (float*)p;  p += (size_t)Nb * 81920;
  float*  rs_fy = (float*)p;  p += (size_t)Nb * 81920;
  float*  cs_fx = (float*)p;  p += (size_t)Nb * 81920;
  float*  cs_fy = (float*)p;  p += (size_t)Nb * 81920;
  float*  invn  = (float*)p;  p += (size_t)Nb * 10240;
  u16*    Sbuf  = (u16*)p;

  // f32 weight views
  float* ln_g = wbuf + ca.cum[0];  float* ln_b = wbuf + ca.cum[1];
  float* w_in = wbuf + ca.cum[2];  float* b_in = wbuf + ca.cum[3];
  float* w_out= wbuf + ca.cum[4]; float* b_out= wbuf + ca.cum[5];
  float* wx7  = wbuf + ca.cum[6];  float* bx7  = wbuf + ca.cum[7];
  float* wx11 = wbuf + ca.cum[8];  float* bx11 = wbuf + ca.cum[9];
  float* wx21 = wbuf + ca.cum[10]; float* bx21 = wbuf + ca.cum[11];
  float* wy7  = wbuf + ca.cum[12]; float* by7  = wbuf + ca.cum[13];
  float* wy11 = wbuf + ca.cum[14]; float* by11 = wbuf + ca.cum[15];
  float* wy21 = wbuf + ca.cum[16]; float* by21 = wbuf + ca.cum[17];

  probe_dtype<<<dim3(1), dim3(256), 0, stream>>>((const u16*)d_in[0], flag);
  cvt_weights<<<dim3(600), dim3(256), 0, stream>>>(ca, wbuf, flag);
  split_w<<<dim3(512), dim3(256), 0, stream>>>(w_in, w_out, wsplit);

  for (int b0 = 0; b0 < NB; b0 += Nb) {
    size_t xoff = (size_t)b0 * NC * NHW;   // element offset of chunk in x / out

    ln_stats<<<dim3(Nb * 25), dim3(256), 0, stream>>>(d_in[0], xoff, flag, stats);
    dw_both<<<dim3(Nb * 256), dim3(256), 0, stream>>>(d_in[0], xoff, flag, stats,
        ln_g, ln_b, wx7, bx7, wx11, bx11, wx21, bx21,
        wy7, by7, wy11, by11, wy21, by21, fxbuf, fybuf);
    pw_mfma_t<0><<<dim3(100, Nb, 2), dim3(256), 0, stream>>>(wsplit, fxbuf, fybuf,
        b_in, nullptr, 0, nullptr, 0, flag);
    transpose_hw<<<dim3(Nb * 256, 2), dim3(256), 0, stream>>>(fxbuf, fybuf, fxT, fyT);
    rowcol_sumsq<<<dim3(Nb * 256, 2), dim3(256), 0, stream>>>(fxbuf, fybuf, rs_fx, rs_fy, cs_fx, cs_fy);
    norm_combine<<<dim3(10 * Nb), dim3(256), 0, stream>>>(rs_fx, rs_fy, cs_fx, cs_fy, invn, Nb);
    gram_softmax_mfma<<<dim3(8, Nb, 2), dim3(256), 0, stream>>>(fxbuf, fybuf, fxT, fyT, invn, Sbuf, Nb);
    apply_hw_mfma<<<dim3(32, 8, Nb), dim3(256), 0, stream>>>(fybuf, fxT, Sbuf, invn, fxbuf, Nb);
    pw_mfma_t<1><<<dim3(100, Nb, 1), dim3(256), 0, stream>>>(wsplit + 131072, fxbuf, nullptr,
        b_out, d_out, xoff, d_in[0], xoff, flag);
  }
  (void)in_sizes; (void)n_in; (void)out_size;
}

// Round 3
// 1175.501 us; speedup vs baseline: 1.6109x; 1.0086x over previous
//
#include <hip/hip_runtime.h>

typedef unsigned short u16;
typedef unsigned int   u32;

#define NB  16
#define NC  256
#define NH  80
#define NW  80
#define NHW 6400

typedef short bf16x8 __attribute__((ext_vector_type(8)));
typedef float f32x4  __attribute__((ext_vector_type(4)));

__device__ __forceinline__ float b2f(u16 u) {
  union { u32 i; float f; } c; c.i = ((u32)u) << 16; return c.f;
}
__device__ __forceinline__ u16 f2b(float f) {
  union { float f; u32 i; } c; c.f = f;
  return (u16)((c.i + 0x7FFFu + ((c.i >> 16) & 1u)) >> 16);
}
// dtype-dispatched input load (flag=1: f32, flag=0: bf16)
__device__ __forceinline__ float ldx(const void* p, size_t i, int f32f) {
  return f32f ? ((const float*)p)[i] : b2f(((const u16*)p)[i]);
}
// resolve dtype flag: host-decided (fh>=0) or device-probed fallback
__device__ __forceinline__ int getf(int fh, const int* flagp) {
  return (fh >= 0) ? fh : *flagp;
}

// ---- K0a (fallback only): detect input dtype (1 = f32, 0 = bf16) ----
__global__ __launch_bounds__(256) void probe_dtype(const u16* __restrict__ x,
                                                   int* __restrict__ flag)
{
  __shared__ int cnt[256];
  int c = 0;
  for (int i = threadIdx.x; i < 262144; i += 256) {
    u16 u = x[i];
    if (((u >> 7) & 0xFF) == 0xFF) c++;
  }
  cnt[threadIdx.x] = c; __syncthreads();
  for (int s = 128; s > 0; s >>= 1) {
    if (threadIdx.x < s) cnt[threadIdx.x] += cnt[threadIdx.x + s];
    __syncthreads();
  }
  if (threadIdx.x == 0) *flag = (cnt[0] > 16) ? 1 : 0;
}

// ---- K0b: convert all 18 weight/bias arrays into one f32 table ----
struct CvtArgs { const void* src[18]; int cum[19]; };

__global__ __launch_bounds__(256) void cvt_weights(CvtArgs a, float* __restrict__ dst,
                                                   int fh, const int* __restrict__ flagp)
{
  int f = getf(fh, flagp);
  int i = blockIdx.x * 256 + threadIdx.x;     // < 153600
  int s = 0;
  while (i >= a.cum[s + 1]) s++;
  int j = i - a.cum[s];
  float v = f ? ((const float*)a.src[s])[j] : b2f(((const u16*)a.src[s])[j]);
  if (!(v == v) || fabsf(v) > 1e30f) v = 0.f;  // scrub
  dst[i] = v;
}

// ---- K0c: split w_in / w_out into bf16 hi+lo pairs for MFMA.
// WB layout: [mat][set][256 o][256 k] u16, mat stride 131072, set stride 65536.
__global__ __launch_bounds__(256) void split_w(const float* __restrict__ w_in,
    const float* __restrict__ w_out, u16* __restrict__ WB)
{
  int i = blockIdx.x * 256 + threadIdx.x;   // < 131072
  int mat = i >> 16, idx = i & 65535;
  float v = (mat ? w_out : w_in)[idx];
  u16 hi = f2b(v);
  u16 lo = f2b(v - b2f(hi));
  WB[mat * 131072 + idx] = hi;
  WB[mat * 131072 + 65536 + idx] = lo;
}

// ---- K1: per-pixel LN stats (mean, rstd) over C ----
__global__ __launch_bounds__(256) void ln_stats(const void* __restrict__ xsrc,
    size_t xoff, int fh, const int* __restrict__ flagp, float2* __restrict__ stats)
{
  int f = getf(fh, flagp);
  int p = blockIdx.x * 256 + threadIdx.x;      // [0, Nb*NHW)
  int bl = p / NHW, hw = p % NHW;
  size_t base = xoff + (size_t)bl * NC * NHW + hw;
  float s1 = 0.f, s2 = 0.f;
  for (int c = 0; c < NC; c++) {
    float v = ldx(xsrc, base + (size_t)c * NHW, f);
    s1 += v; s2 += v * v;
  }
  float mean = s1 * (1.f / 256.f);
  float var  = s2 * (1.f / 256.f) - mean * mean;
  stats[p] = make_float2(mean, rsqrtf(var + 1e-5f));
}

// ---- K2: fused LN + BOTH depthwise convs from one LDS-staged plane ----
__global__ __launch_bounds__(256) void dw_both(const void* __restrict__ xsrc,
    size_t xoff, int fh, const int* __restrict__ flagp,
    const float2* __restrict__ stats,
    const float* __restrict__ g, const float* __restrict__ bt,
    const float* __restrict__ wx7,  const float* __restrict__ bx7,
    const float* __restrict__ wx11, const float* __restrict__ bx11,
    const float* __restrict__ wx21, const float* __restrict__ bx21,
    const float* __restrict__ wy7,  const float* __restrict__ by7,
    const float* __restrict__ wy11, const float* __restrict__ by11,
    const float* __restrict__ wy21, const float* __restrict__ by21,
    u16* __restrict__ sx, u16* __restrict__ sy)
{
  __shared__ float xn[80][81];          // normalized plane, +1 pad
  __shared__ float cwx[21], cwy[21];
  __shared__ float cbx, cby;
  int f = getf(fh, flagp);
  int bc = blockIdx.x;                  // bl*256 + c
  int c  = bc & 255;
  int bl = bc >> 8;
  int t = threadIdx.x;
  if (t < 21) {
    float v = wx21[c * 21 + t];
    if (t >= 5 && t <= 15) v += wx11[c * 11 + t - 5];
    if (t >= 7 && t <= 13) v += wx7[c * 7 + t - 7];
    cwx[t] = v;
  } else if (t < 42) {
    int j = t - 21;
    float v = wy21[c * 21 + j];
    if (j >= 5 && j <= 15) v += wy11[c * 11 + j - 5];
    if (j >= 7 && j <= 13) v += wy7[c * 7 + j - 7];
    cwy[j] = v;
  } else if (t == 42) { cbx = bx7[c] + bx11[c] + bx21[c]; }
  else if (t == 43)   { cby = by7[c] + by11[c] + by21[c]; }
  float cg = g[c], cbt = bt[c];
  size_t xrow = xoff + (size_t)bc * NHW;
  const float2* st = stats + (size_t)bl * NHW;
  for (int i = t; i < NHW; i += 256) {
    float v = ldx(xsrc, xrow + i, f);
    float2 s = st[i];
    xn[i / 80][i % 80] = (v - s.x) * s.y * cg + cbt;
  }
  __syncthreads();
  float bxv = cbx, byv = cby;
  size_t obase = (size_t)bc * NHW;
  for (int k = 0; k < 25; k++) {
    int p = t + 256 * k;
    int h = p / 80, w = p % 80;
    float ax = bxv, ay = byv;
    #pragma unroll
    for (int d = -10; d <= 10; d++) {
      int wp = w + d;
      if (wp >= 0 && wp < NW) ax += cwx[d + 10] * xn[h][wp];
      int hp = h + d;
      if (hp >= 0 && hp < NH) ay += cwy[d + 10] * xn[hp][w];
    }
    sx[obase + p] = f2b(ax);
    sy[obase + p] = f2b(ay);
  }
}

// ---- K3/K8: MFMA pointwise conv. C[o][p] = sum_k W[o][k]*In[k][p], W split
// into bf16 hi+lo. One block = full 256 o x 64 px strip of one batch.
// FINAL=1: out = acc + 2*bias + x, dtype-dispatched; else in-place bf16 + bias.
template<int FINAL>
__global__ __launch_bounds__(256) void pw_mfma_t(const u16* __restrict__ WB,
    u16* io0, u16* io1, const float* __restrict__ bias,
    void* __restrict__ OutBase, size_t out_off,
    const void* __restrict__ xsrc, size_t xoff,
    int fh, const int* __restrict__ flagp)
{
  __shared__ u16 S[32768];              // 64 KB: InT = S[0:16384], Wp = S[16384:]
  u16* InT = S;
  u16* Wp  = S + 16384;
  int bl = blockIdx.y;
  int p0 = blockIdx.x * 64;
  int t  = threadIdx.x;
  int lane = t & 63, wid = t >> 6, lg = lane >> 4, lr = lane & 15;
  u16* io = (FINAL || blockIdx.z == 0) ? io0 : io1;

  // ---- stage InT with register 8x8 transpose; swizzle col8 ^= (px&7) ----
  {
    int kb = t >> 3, pb = t & 7;
    const u16* src = io + (size_t)bl * NC * NHW + p0 + pb * 8;
    u32 r[8][4];
    #pragma unroll
    for (int i = 0; i < 8; i++) {
      uint4 v = *(const uint4*)(src + (size_t)(kb * 8 + i) * NHW);
      r[i][0] = v.x; r[i][1] = v.y; r[i][2] = v.z; r[i][3] = v.w;
    }
    #pragma unroll
    for (int j = 0; j < 8; j++) {
      u32 w[4];
      #pragma unroll
      for (int m = 0; m < 4; m++) {
        u32 a = r[2 * m][j >> 1], b = r[2 * m + 1][j >> 1];
        w[m] = (j & 1) ? ((a >> 16) | (b & 0xFFFF0000u))
                       : ((a & 0xFFFFu) | (b << 16));
      }
      int p = pb * 8 + j;
      *(uint4*)&InT[p * 256 + ((kb ^ j) * 8)] = make_uint4(w[0], w[1], w[2], w[3]);
    }
  }
  __syncthreads();

  f32x4 acc[4][4];
  #pragma unroll
  for (int m = 0; m < 4; m++)
    #pragma unroll
    for (int n = 0; n < 4; n++)
      acc[m][n] = (f32x4){0.f, 0.f, 0.f, 0.f};

  for (int ch = 0; ch < 8; ch++) {
    // stage W panel (hi unit 0..3 | lo unit 4..7) for k = ch*32..+31
    #pragma unroll
    for (int rep = 0; rep < 8; rep++) {
      int o = rep * 32 + (t >> 3), sg = t & 7;
      uint4 v = *(const uint4*)(WB + (sg >> 2) * 65536 + o * 256 + ch * 32 + (sg & 3) * 8);
      *(uint4*)&Wp[o * 64 + ((sg ^ (o & 7)) * 8)] = v;
    }
    __syncthreads();
    bf16x8 bfr[4];
    #pragma unroll
    for (int n = 0; n < 4; n++) {
      int px = n * 16 + lr;
      bfr[n] = *(const bf16x8*)&InT[px * 256 + (((ch * 4 + lg) ^ (px & 7)) * 8)];
    }
    #pragma unroll
    for (int m = 0; m < 4; m++) {
      int o = (wid * 4 + m) * 16 + lr;
      bf16x8 ahi = *(const bf16x8*)&Wp[o * 64 + ((lg ^ (o & 7)) * 8)];
      bf16x8 alo = *(const bf16x8*)&Wp[o * 64 + (((4 + lg) ^ (o & 7)) * 8)];
      #pragma unroll
      for (int n = 0; n < 4; n++) {
        acc[m][n] = __builtin_amdgcn_mfma_f32_16x16x32_bf16(ahi, bfr[n], acc[m][n], 0, 0, 0);
        acc[m][n] = __builtin_amdgcn_mfma_f32_16x16x32_bf16(alo, bfr[n], acc[m][n], 0, 0, 0);
      }
    }
    __syncthreads();
  }

  // ---- epilogue via LDS round-trip for vectorized global stores ----
  if (FINAL) {
    float* Otf = (float*)S;             // [256 o][64 px] f32, swizzled
    #pragma unroll
    for (int m = 0; m < 4; m++)
      #pragma unroll
      for (int r = 0; r < 4; r++) {
        int o = (wid * 4 + m) * 16 + 4 * lg + r;
        float bv = 2.f * bias[o];
        #pragma unroll
        for (int n = 0; n < 4; n++) {
          int px = n * 16 + lr;
          Otf[o * 64 + (px ^ ((o & 7) * 8))] = acc[m][n][r] + bv;
        }
      }
    __syncthreads();
    int f = getf(fh, flagp);
    size_t gbase = ((size_t)bl * NC + t) * NHW + p0;
    #pragma unroll
    for (int j2 = 0; j2 < 16; j2++) {
      float4 v = *(float4*)&Otf[t * 64 + ((j2 * 4) ^ ((t & 7) * 8))];
      size_t gi = gbase + j2 * 4;
      if (f) {
        const float* xp = (const float*)xsrc + xoff + gi;
        v.x += xp[0]; v.y += xp[1]; v.z += xp[2]; v.w += xp[3];
        *(float4*)((float*)OutBase + out_off + gi) = v;
      } else {
        ushort4 xv = *(const ushort4*)((const u16*)xsrc + xoff + gi);
        ushort4 ov;
        ov.x = f2b(v.x + b2f(xv.x)); ov.y = f2b(v.y + b2f(xv.y));
        ov.z = f2b(v.z + b2f(xv.z)); ov.w = f2b(v.w + b2f(xv.w));
        *(ushort4*)((u16*)OutBase + out_off + gi) = ov;
      }
    }
  } else {
    u16* Ot = S;                        // [256 o][64 px] u16, swizzled
    #pragma unroll
    for (int m = 0; m < 4; m++)
      #pragma unroll
      for (int r = 0; r < 4; r++) {
        int o = (wid * 4 + m) * 16 + 4 * lg + r;
        float bv = bias[o];
        #pragma unroll
        for (int n = 0; n < 4; n++) {
          int px = n * 16 + lr;
          Ot[o * 64 + (px ^ ((o & 7) * 8))] = f2b(acc[m][n][r] + bv);
        }
      }
    __syncthreads();
    u16* orow = io + ((size_t)bl * NC + t) * NHW + p0;
    #pragma unroll
    for (int j = 0; j < 8; j++) {
      uint4 v = *(uint4*)&Ot[t * 64 + ((j ^ (t & 7)) * 8)];
      *(uint4*)(orow + j * 8) = v;
    }
  }
  (void)OutBase; (void)out_off; (void)xsrc; (void)xoff; (void)flagp; (void)io1;
}

// ---- K-T fused: per-plane 80x80 bf16 transpose + row/col sum of squares.
// One read of fx/fy serves both the [c][h][w]->[c][w][h] transpose and the
// rs/cs sumsq reductions (was two full-buffer read passes). ----
__global__ __launch_bounds__(256) void transpose_sumsq(const u16* __restrict__ fx,
    const u16* __restrict__ fy, u16* __restrict__ fxT, u16* __restrict__ fyT,
    float* __restrict__ rs_fx, float* __restrict__ rs_fy,
    float* __restrict__ cs_fx, float* __restrict__ cs_fy)
{
  __shared__ u16 tile[80][81];
  int pl = blockIdx.x, ten = blockIdx.y;
  const u16* src = (ten ? fy : fx) + (size_t)pl * NHW;
  u16*       dst = (ten ? fyT : fxT) + (size_t)pl * NHW;
  int t = threadIdx.x;
  for (int i = t; i < NHW; i += 256) tile[i / 80][i % 80] = src[i];
  __syncthreads();
  for (int i = t; i < NHW; i += 256) dst[i] = tile[i % 80][i / 80];
  if (t < 80) {
    float s = 0.f;
    #pragma unroll
    for (int k = 0; k < 80; k++) { float v = b2f(tile[t][k]); s += v * v; }
    (ten ? rs_fy : rs_fx)[pl * 80 + t] = s;
  } else if (t < 160) {
    int w = t - 80; float s = 0.f;
    #pragma unroll
    for (int h = 0; h < 80; h++) { float v = b2f(tile[h][w]); s += v * v; }
    (ten ? cs_fy : cs_fx)[pl * 80 + w] = s;
  }
}

// ---- K5: combine over ci -> inverse norms ----
__global__ __launch_bounds__(256) void norm_combine(const float* __restrict__ rs_fx,
    const float* __restrict__ rs_fy, const float* __restrict__ cs_fx,
    const float* __restrict__ cs_fy, float* __restrict__ invn, int Nb)
{
  int t = blockIdx.x * 256 + threadIdx.x;   // 4*Nb*640 total
  int blk = Nb * 640;
  int side = t / blk, r = t % blk;
  int b = r / 640, rem = r % 640, hd = rem / 80, row = rem % 80;
  const float* src = (side == 0) ? rs_fy : (side == 1) ? rs_fx : (side == 2) ? cs_fx : cs_fy;
  size_t base = (size_t)(b * 256 + hd * 32) * 80 + row;
  float s = 0.f;
  #pragma unroll
  for (int ci = 0; ci < 32; ci++) s += src[base + ci * 80];
  invn[t] = 1.f / fmaxf(sqrtf(s), 1e-12f);
}

// ---- MFMA helpers for 80x80 Gram-style tiles ----
template<int T0, int NT>
__device__ __forceinline__ void gram_wave(const u16* pa, const u16* pb,
                                          int lg, int lr, f32x4* acc)
{
  constexpr int MLO = T0 / 5;
  #pragma unroll
  for (int ch = 0; ch < 3; ch++) {
    bool tz = (ch == 2) && (lg >= 2);
    int kk = ch * 32 + 8 * lg;
    if (tz) kk = 0;
    bf16x8 af[2], bf[5];
    #pragma unroll
    for (int m = 0; m < 2; m++)
      af[m] = *(const bf16x8*)(pa + ((MLO + m) * 16 + lr) * 80 + kk);
    #pragma unroll
    for (int n = 0; n < 5; n++)
      bf[n] = *(const bf16x8*)(pb + (n * 16 + lr) * 80 + kk);
    if (tz) {
      bf16x8 z = {0, 0, 0, 0, 0, 0, 0, 0};
      af[0] = z; af[1] = z;
    }
    #pragma unroll
    for (int j = 0; j < NT; j++) {
      acc[j] = __builtin_amdgcn_mfma_f32_16x16x32_bf16(
          af[(T0 + j) / 5 - MLO], bf[(T0 + j) % 5], acc[j], 0, 0, 0);
    }
  }
}

template<int T0, int NT>
__device__ __forceinline__ void gram_all(const u16* Ab, const u16* Bb,
                                         int lg, int lr, f32x4* acc)
{
  for (int ci = 0; ci < 32; ci++)
    gram_wave<T0, NT>(Ab + (size_t)ci * NHW, Bb + (size_t)ci * NHW, lg, lr, acc);
}

// ---- K6: MFMA Gram (sum over 32 ci) + cosine scale + softmax -> Sbuf ----
__global__ __launch_bounds__(256) void gram_softmax_mfma(const u16* __restrict__ fx,
    const u16* __restrict__ fy, const u16* __restrict__ fxT, const u16* __restrict__ fyT,
    const float* __restrict__ invn, u16* __restrict__ Sbuf, int Nb)
{
  __shared__ float At[80][81];
  int hd = blockIdx.x, b = blockIdx.y, axis = blockIdx.z;
  size_t sl0 = (size_t)(b * 256 + hd * 32) * NHW;
  const u16* Ab = (axis ? fxT : fy) + sl0;
  const u16* Bb = (axis ? fyT : fx) + sl0;
  int t = threadIdx.x, lane = t & 63, wid = t >> 6;
  int lg = lane >> 4, lr = lane & 15;
  f32x4 acc0 = {0.f, 0.f, 0.f, 0.f};
  f32x4 acc[7];
  #pragma unroll
  for (int j = 0; j < 7; j++) acc[j] = acc0;
  if      (wid == 0) gram_all<0, 7>(Ab, Bb, lg, lr, acc);
  else if (wid == 1) gram_all<7, 6>(Ab, Bb, lg, lr, acc);
  else if (wid == 2) gram_all<13, 6>(Ab, Bb, lg, lr, acc);
  else               gram_all<19, 6>(Ab, Bb, lg, lr, acc);
  int blk = Nb * 640;
  int rowbase = (b * 8 + hd) * 80;
  const float* invq = invn + (axis ? 2 * blk : 0)   + rowbase;
  const float* invk = invn + (axis ? 3 * blk : blk) + rowbase;
  int t0  = wid ? 6 * wid + 1 : 0;
  int cnt = wid ? 6 : 7;
  #pragma unroll
  for (int j = 0; j < 7; j++) {
    if (j < cnt) {
      int tt = t0 + j, m = tt / 5, n = tt % 5;
      int col = n * 16 + lr;
      float ik = invk[col];
      #pragma unroll
      for (int r = 0; r < 4; r++) {
        int row = m * 16 + 4 * lg + r;
        float gv = acc[j][r] * invq[row] * ik;
        At[row][col] = fminf(fmaxf(gv, -8.f), 8.f);  // |cos|<=1; NaN->-8
      }
    }
  }
  __syncthreads();
  u16* Sg = Sbuf + ((size_t)(axis * Nb * 8 + b * 8 + hd)) * NHW;
  if (t < 80) {
    float mx = -1e30f;
    for (int j = 0; j < 80; j++) mx = fmaxf(mx, At[t][j]);
    float s = 0.f;
    for (int j = 0; j < 80; j++) s += __expf(At[t][j] - mx);
    float inv = 1.f / s;
    for (int j = 0; j < 80; j++) Sg[t * 80 + j] = f2b(__expf(At[t][j] - mx) * inv);
  }
}

// ---- K7: MFMA fused H+W attention apply, IN PLACE over fx slice ----
template<int T0, int NT>
__device__ __forceinline__ void apply_wave(const u16* SH, const u16* fxT,
    const u16* fyP, const u16* SW, int lg, int lr, f32x4* acc)
{
  constexpr int MLO = T0 / 5;
  for (int ch = 0; ch < 3; ch++) {
    bool tz = (ch == 2) && (lg >= 2);
    int kk = ch * 32 + 8 * lg;
    if (tz) kk = 0;
    bf16x8 a1[2], a2[2], b1[5], b2[5];
    #pragma unroll
    for (int m = 0; m < 2; m++) {
      a1[m] = *(const bf16x8*)(SH  + ((MLO + m) * 16 + lr) * 80 + kk);
      a2[m] = *(const bf16x8*)(fyP + ((MLO + m) * 16 + lr) * 80 + kk);
    }
    #pragma unroll
    for (int n = 0; n < 5; n++) {
      b1[n] = *(const bf16x8*)(fxT + (n * 16 + lr) * 80 + kk);
      b2[n] = *(const bf16x8*)(SW  + (n * 16 + lr) * 80 + kk);
    }
    if (tz) {
      bf16x8 z = {0, 0, 0, 0, 0, 0, 0, 0};
      a1[0] = z; a1[1] = z; a2[0] = z; a2[1] = z;
    }
    #pragma unroll
    for (int j = 0; j < NT; j++) {
      acc[j] = __builtin_amdgcn_mfma_f32_16x16x32_bf16(
          a1[(T0 + j) / 5 - MLO], b1[(T0 + j) % 5], acc[j], 0, 0, 0);
      acc[j] = __builtin_amdgcn_mfma_f32_16x16x32_bf16(
          a2[(T0 + j) / 5 - MLO], b2[(T0 + j) % 5], acc[j], 0, 0, 0);
    }
  }
}

__global__ __launch_bounds__(256, 2) void apply_hw_mfma(const u16* __restrict__ fy_g,
    const u16* __restrict__ fxT_g, const u16* __restrict__ Sbuf,
    const float* __restrict__ invn, u16* fx_io, int Nb)
{
  int ci = blockIdx.x, hd = blockIdx.y, b = blockIdx.z;
  size_t off = (size_t)(b * 256 + hd * 32 + ci) * NHW;
  const u16* SgH = Sbuf + (size_t)(b * 8 + hd) * NHW;
  const u16* SgW = Sbuf + ((size_t)(Nb * 8) + b * 8 + hd) * NHW;
  const u16* fyP = fy_g + off;
  const u16* fxT = fxT_g + off;
  int t = threadIdx.x, lane = t & 63, wid = t >> 6;
  int lg = lane >> 4, lr = lane & 15;
  f32x4 acc0 = {0.f, 0.f, 0.f, 0.f};
  f32x4 acc[7];
  #pragma unroll
  for (int j = 0; j < 7; j++) acc[j] = acc0;
  if      (wid == 0) apply_wave<0, 7>(SgH, fxT, fyP, SgW, lg, lr, acc);
  else if (wid == 1) apply_wave<7, 6>(SgH, fxT, fyP, SgW, lg, lr, acc);
  else if (wid == 2) apply_wave<13, 6>(SgH, fxT, fyP, SgW, lg, lr, acc);
  else               apply_wave<19, 6>(SgH, fxT, fyP, SgW, lg, lr, acc);
  const float* invqH = invn + (b * 8 + hd) * 80;                 // H_fy(q)
  const float* invqW = invn + 2 * Nb * 640 + (b * 8 + hd) * 80;  // W_fx(q)
  int t0  = wid ? 6 * wid + 1 : 0;
  int cnt = wid ? 6 : 7;
  #pragma unroll
  for (int j = 0; j < 7; j++) {
    if (j < cnt) {
      int tt = t0 + j, m = tt / 5, n = tt % 5;
      int col = n * 16 + lr;
      float ivW = invqW[col];
      #pragma unroll
      for (int r = 0; r < 4; r++) {
        int row = m * 16 + 4 * lg + r;
        size_t ix = off + row * 80 + col;
        float v = acc[j][r] + b2f(fy_g[ix]) * invqH[row] + b2f(fx_io[ix]) * ivW;
        fx_io[ix] = f2b(v);
      }
    }
  }
}

extern "C" void kernel_launch(void* const* d_in, const int* in_sizes, int n_in,
                              void* d_out, int out_size, void* d_ws, size_t ws_size,
                              hipStream_t stream) {
  // Weight conversion table: d_in[1..18] in setup_inputs order.
  const int wsz[18] = {256, 256, 65536, 256, 65536, 256,
                       1792, 256, 2816, 256, 5376, 256,
                       1792, 256, 2816, 256, 5376, 256};
  CvtArgs ca;
  int cum = 0;
  for (int i = 0; i < 18; i++) { ca.src[i] = d_in[i + 1]; ca.cum[i] = cum; cum += wsz[i]; }
  ca.cum[18] = cum;   // 153600

  // Host-side dtype detection from input byte size (x: 26,214,400 elements).
  // Falls back to the on-device probe only if sizes are unrecognizable.
  int hostf = -1;
  if (in_sizes && n_in > 0) {
    if      (in_sizes[0] == 104857600) hostf = 1;   // f32
    else if (in_sizes[0] == 52428800)  hostf = 0;   // bf16
  }

  // ws layout: flag(16) | wbuf(614400) | wsplit(524288) | per-chunk buffers.
  int Nb = 1;
  for (int cand = 16; cand >= 1; cand >>= 1) {
    size_t need = (size_t)cand * 13701120 + 614416 + 524288;
    if (need <= ws_size) { Nb = cand; break; }
  }
  char* p = (char*)d_ws;
  int*    flag  = (int*)p;    p += 16;
  float*  wbuf  = (float*)p;  p += 614400;
  u16*    wsplit= (u16*)p;    p += 524288;     // [2 mat][2 set][256][256] bf16
  u16*    fxbuf = (u16*)p;    p += (size_t)Nb * 3276800;
  u16*    fybuf = (u16*)p;    p += (size_t)Nb * 3276800;
  u16*    fxT   = (u16*)p;    p += (size_t)Nb * 3276800;
  u16*    fyT   = (u16*)p;    p += (size_t)Nb * 3276800;
  float2* stats = (float2*)p; p += (size_t)Nb * 51200;
  float*  rs_fx = (float*)p;  p += (size_t)Nb * 81920;
  float*  rs_fy = (float*)p;  p += (size_t)Nb * 81920;
  float*  cs_fx = (float*)p;  p += (size_t)Nb * 81920;
  float*  cs_fy = (float*)p;  p += (size_t)Nb * 81920;
  float*  invn  = (float*)p;  p += (size_t)Nb * 10240;
  u16*    Sbuf  = (u16*)p;

  // f32 weight views
  float* ln_g = wbuf + ca.cum[0];  float* ln_b = wbuf + ca.cum[1];
  float* w_in = wbuf + ca.cum[2];  float* b_in = wbuf + ca.cum[3];
  float* w_out= wbuf + ca.cum[4]; float* b_out= wbuf + ca.cum[5];
  float* wx7  = wbuf + ca.cum[6];  float* bx7  = wbuf + ca.cum[7];
  float* wx11 = wbuf + ca.cum[8];  float* bx11 = wbuf + ca.cum[9];
  float* wx21 = wbuf + ca.cum[10]; float* bx21 = wbuf + ca.cum[11];
  float* wy7  = wbuf + ca.cum[12]; float* by7  = wbuf + ca.cum[13];
  float* wy11 = wbuf + ca.cum[14]; float* by11 = wbuf + ca.cum[15];
  float* wy21 = wbuf + ca.cum[16]; float* by21 = wbuf + ca.cum[17];

  if (hostf < 0)
    probe_dtype<<<dim3(1), dim3(256), 0, stream>>>((const u16*)d_in[0], flag);
  cvt_weights<<<dim3(600), dim3(256), 0, stream>>>(ca, wbuf, hostf, flag);
  split_w<<<dim3(512), dim3(256), 0, stream>>>(w_in, w_out, wsplit);

  for (int b0 = 0; b0 < NB; b0 += Nb) {
    size_t xoff = (size_t)b0 * NC * NHW;   // element offset of chunk in x / out

    ln_stats<<<dim3(Nb * 25), dim3(256), 0, stream>>>(d_in[0], xoff, hostf, flag, stats);
    dw_both<<<dim3(Nb * 256), dim3(256), 0, stream>>>(d_in[0], xoff, hostf, flag, stats,
        ln_g, ln_b, wx7, bx7, wx11, bx11, wx21, bx21,
        wy7, by7, wy11, by11, wy21, by21, fxbuf, fybuf);
    pw_mfma_t<0><<<dim3(100, Nb, 2), dim3(256), 0, stream>>>(wsplit, fxbuf, fybuf,
        b_in, nullptr, 0, nullptr, 0, hostf, flag);
    transpose_sumsq<<<dim3(Nb * 256, 2), dim3(256), 0, stream>>>(fxbuf, fybuf, fxT, fyT,
        rs_fx, rs_fy, cs_fx, cs_fy);
    norm_combine<<<dim3(10 * Nb), dim3(256), 0, stream>>>(rs_fx, rs_fy, cs_fx, cs_fy, invn, Nb);
    gram_softmax_mfma<<<dim3(8, Nb, 2), dim3(256), 0, stream>>>(fxbuf, fybuf, fxT, fyT, invn, Sbuf, Nb);
    apply_hw_mfma<<<dim3(32, 8, Nb), dim3(256), 0, stream>>>(fybuf, fxT, Sbuf, invn, fxbuf, Nb);
    pw_mfma_t<1><<<dim3(100, Nb, 1), dim3(256), 0, stream>>>(wsplit + 131072, fxbuf, nullptr,
        b_out, d_out, xoff, d_in[0], xoff, hostf, flag);
  }
  (void)in_sizes; (void)n_in; (void)out_size;
}

// Round 4
// 953.409 us; speedup vs baseline: 1.9862x; 1.2329x over previous
//
#include <hip/hip_runtime.h>

typedef unsigned short u16;
typedef unsigned int   u32;

#define NB  16
#define NC  256
#define NH  80
#define NW  80
#define NHW 6400

typedef short bf16x8 __attribute__((ext_vector_type(8)));
typedef float f32x4  __attribute__((ext_vector_type(4)));

__device__ __forceinline__ float b2f(u16 u) {
  union { u32 i; float f; } c; c.i = ((u32)u) << 16; return c.f;
}
__device__ __forceinline__ u16 f2b(float f) {
  union { float f; u32 i; } c; c.f = f;
  return (u16)((c.i + 0x7FFFu + ((c.i >> 16) & 1u)) >> 16);
}
// dtype-dispatched input load (flag=1: f32, flag=0: bf16)
__device__ __forceinline__ float ldx(const void* p, size_t i, int f32f) {
  return f32f ? ((const float*)p)[i] : b2f(((const u16*)p)[i]);
}
// resolve dtype flag: host-decided (fh>=0) or device-probed fallback
__device__ __forceinline__ int getf(int fh, const int* flagp) {
  return (fh >= 0) ? fh : *flagp;
}

// ---- K0a (fallback only): fast parallel dtype probe.
// flag[0] = decision, flag[1] = hit counter. Same 262144-word sample and
// threshold (>16) as the original serial probe; 64 blocks x 256 thr x 16 words.
__global__ void probe_init(int* __restrict__ flag) { flag[0] = 0; flag[1] = 0; }

__global__ __launch_bounds__(256) void probe_count(const u16* __restrict__ x,
                                                   int* __restrict__ flag)
{
  __shared__ int cnt[256];
  int base = (blockIdx.x * 256 + threadIdx.x) * 16;   // 64*256*16 = 262144
  int c = 0;
  uint4 v0 = *(const uint4*)(x + base);
  uint4 v1 = *(const uint4*)(x + base + 8);
  u32 w[8] = {v0.x, v0.y, v0.z, v0.w, v1.x, v1.y, v1.z, v1.w};
  #pragma unroll
  for (int j = 0; j < 8; j++) {
    if (((w[j] >> 7)  & 0xFFu) == 0xFFu) c++;
    if (((w[j] >> 23) & 0xFFu) == 0xFFu) c++;
  }
  cnt[threadIdx.x] = c; __syncthreads();
  for (int s = 128; s > 0; s >>= 1) {
    if (threadIdx.x < s) cnt[threadIdx.x] += cnt[threadIdx.x + s];
    __syncthreads();
  }
  if (threadIdx.x == 0) atomicAdd(&flag[1], cnt[0]);
}

__global__ void probe_decide(int* __restrict__ flag) {
  flag[0] = (flag[1] > 16) ? 1 : 0;
}

// ---- K0b: convert all 18 weight/bias arrays into one f32 table ----
struct CvtArgs { const void* src[18]; int cum[19]; };

__global__ __launch_bounds__(256) void cvt_weights(CvtArgs a, float* __restrict__ dst,
                                                   int fh, const int* __restrict__ flagp)
{
  int f = getf(fh, flagp);
  int i = blockIdx.x * 256 + threadIdx.x;     // < 153600
  int s = 0;
  while (i >= a.cum[s + 1]) s++;
  int j = i - a.cum[s];
  float v = f ? ((const float*)a.src[s])[j] : b2f(((const u16*)a.src[s])[j]);
  if (!(v == v) || fabsf(v) > 1e30f) v = 0.f;  // scrub
  dst[i] = v;
}

// ---- K0c: split w_in / w_out into bf16 hi+lo pairs for MFMA.
// WB layout: [mat][set][256 o][256 k] u16, mat stride 131072, set stride 65536.
__global__ __launch_bounds__(256) void split_w(const float* __restrict__ w_in,
    const float* __restrict__ w_out, u16* __restrict__ WB)
{
  int i = blockIdx.x * 256 + threadIdx.x;   // < 131072
  int mat = i >> 16, idx = i & 65535;
  float v = (mat ? w_out : w_in)[idx];
  u16 hi = f2b(v);
  u16 lo = f2b(v - b2f(hi));
  WB[mat * 131072 + idx] = hi;
  WB[mat * 131072 + 65536 + idx] = lo;
}

// ---- K1: per-pixel LN stats (mean, rstd) over C ----
__global__ __launch_bounds__(256) void ln_stats(const void* __restrict__ xsrc,
    size_t xoff, int fh, const int* __restrict__ flagp, float2* __restrict__ stats)
{
  int f = getf(fh, flagp);
  int p = blockIdx.x * 256 + threadIdx.x;      // [0, Nb*NHW)
  int bl = p / NHW, hw = p % NHW;
  size_t base = xoff + (size_t)bl * NC * NHW + hw;
  float s1 = 0.f, s2 = 0.f;
  for (int c = 0; c < NC; c++) {
    float v = ldx(xsrc, base + (size_t)c * NHW, f);
    s1 += v; s2 += v * v;
  }
  float mean = s1 * (1.f / 256.f);
  float var  = s2 * (1.f / 256.f) - mean * mean;
  stats[p] = make_float2(mean, rsqrtf(var + 1e-5f));
}

// ---- K2: fused LN + BOTH depthwise convs from one LDS-staged plane ----
__global__ __launch_bounds__(256) void dw_both(const void* __restrict__ xsrc,
    size_t xoff, int fh, const int* __restrict__ flagp,
    const float2* __restrict__ stats,
    const float* __restrict__ g, const float* __restrict__ bt,
    const float* __restrict__ wx7,  const float* __restrict__ bx7,
    const float* __restrict__ wx11, const float* __restrict__ bx11,
    const float* __restrict__ wx21, const float* __restrict__ bx21,
    const float* __restrict__ wy7,  const float* __restrict__ by7,
    const float* __restrict__ wy11, const float* __restrict__ by11,
    const float* __restrict__ wy21, const float* __restrict__ by21,
    u16* __restrict__ sx, u16* __restrict__ sy)
{
  __shared__ float xn[80][81];          // normalized plane, +1 pad
  __shared__ float cwx[21], cwy[21];
  __shared__ float cbx, cby;
  int f = getf(fh, flagp);
  int bc = blockIdx.x;                  // bl*256 + c
  int c  = bc & 255;
  int bl = bc >> 8;
  int t = threadIdx.x;
  if (t < 21) {
    float v = wx21[c * 21 + t];
    if (t >= 5 && t <= 15) v += wx11[c * 11 + t - 5];
    if (t >= 7 && t <= 13) v += wx7[c * 7 + t - 7];
    cwx[t] = v;
  } else if (t < 42) {
    int j = t - 21;
    float v = wy21[c * 21 + j];
    if (j >= 5 && j <= 15) v += wy11[c * 11 + j - 5];
    if (j >= 7 && j <= 13) v += wy7[c * 7 + j - 7];
    cwy[j] = v;
  } else if (t == 42) { cbx = bx7[c] + bx11[c] + bx21[c]; }
  else if (t == 43)   { cby = by7[c] + by11[c] + by21[c]; }
  float cg = g[c], cbt = bt[c];
  size_t xrow = xoff + (size_t)bc * NHW;
  const float2* st = stats + (size_t)bl * NHW;
  for (int i = t; i < NHW; i += 256) {
    float v = ldx(xsrc, xrow + i, f);
    float2 s = st[i];
    xn[i / 80][i % 80] = (v - s.x) * s.y * cg + cbt;
  }
  __syncthreads();
  float bxv = cbx, byv = cby;
  size_t obase = (size_t)bc * NHW;
  for (int k = 0; k < 25; k++) {
    int p = t + 256 * k;
    int h = p / 80, w = p % 80;
    float ax = bxv, ay = byv;
    #pragma unroll
    for (int d = -10; d <= 10; d++) {
      int wp = w + d;
      if (wp >= 0 && wp < NW) ax += cwx[d + 10] * xn[h][wp];
      int hp = h + d;
      if (hp >= 0 && hp < NH) ay += cwy[d + 10] * xn[hp][w];
    }
    sx[obase + p] = f2b(ax);
    sy[obase + p] = f2b(ay);
  }
}

// ---- K3/K8: MFMA pointwise conv. C[o][p] = sum_k W[o][k]*In[k][p], W split
// into bf16 hi+lo. One block = full 256 o x 64 px strip of one batch.
// FINAL=1: out = acc + 2*bias + x, dtype-dispatched; else in-place bf16 + bias.
template<int FINAL>
__global__ __launch_bounds__(256) void pw_mfma_t(const u16* __restrict__ WB,
    u16* io0, u16* io1, const float* __restrict__ bias,
    void* __restrict__ OutBase, size_t out_off,
    const void* __restrict__ xsrc, size_t xoff,
    int fh, const int* __restrict__ flagp)
{
  __shared__ u16 S[32768];              // 64 KB: InT = S[0:16384], Wp = S[16384:]
  u16* InT = S;
  u16* Wp  = S + 16384;
  int bl = blockIdx.y;
  int p0 = blockIdx.x * 64;
  int t  = threadIdx.x;
  int lane = t & 63, wid = t >> 6, lg = lane >> 4, lr = lane & 15;
  u16* io = (FINAL || blockIdx.z == 0) ? io0 : io1;

  // ---- stage InT with register 8x8 transpose; swizzle col8 ^= (px&7) ----
  {
    int kb = t >> 3, pb = t & 7;
    const u16* src = io + (size_t)bl * NC * NHW + p0 + pb * 8;
    u32 r[8][4];
    #pragma unroll
    for (int i = 0; i < 8; i++) {
      uint4 v = *(const uint4*)(src + (size_t)(kb * 8 + i) * NHW);
      r[i][0] = v.x; r[i][1] = v.y; r[i][2] = v.z; r[i][3] = v.w;
    }
    #pragma unroll
    for (int j = 0; j < 8; j++) {
      u32 w[4];
      #pragma unroll
      for (int m = 0; m < 4; m++) {
        u32 a = r[2 * m][j >> 1], b = r[2 * m + 1][j >> 1];
        w[m] = (j & 1) ? ((a >> 16) | (b & 0xFFFF0000u))
                       : ((a & 0xFFFFu) | (b << 16));
      }
      int p = pb * 8 + j;
      *(uint4*)&InT[p * 256 + ((kb ^ j) * 8)] = make_uint4(w[0], w[1], w[2], w[3]);
    }
  }
  __syncthreads();

  f32x4 acc[4][4];
  #pragma unroll
  for (int m = 0; m < 4; m++)
    #pragma unroll
    for (int n = 0; n < 4; n++)
      acc[m][n] = (f32x4){0.f, 0.f, 0.f, 0.f};

  for (int ch = 0; ch < 8; ch++) {
    // stage W panel (hi unit 0..3 | lo unit 4..7) for k = ch*32..+31
    #pragma unroll
    for (int rep = 0; rep < 8; rep++) {
      int o = rep * 32 + (t >> 3), sg = t & 7;
      uint4 v = *(const uint4*)(WB + (sg >> 2) * 65536 + o * 256 + ch * 32 + (sg & 3) * 8);
      *(uint4*)&Wp[o * 64 + ((sg ^ (o & 7)) * 8)] = v;
    }
    __syncthreads();
    bf16x8 bfr[4];
    #pragma unroll
    for (int n = 0; n < 4; n++) {
      int px = n * 16 + lr;
      bfr[n] = *(const bf16x8*)&InT[px * 256 + (((ch * 4 + lg) ^ (px & 7)) * 8)];
    }
    #pragma unroll
    for (int m = 0; m < 4; m++) {
      int o = (wid * 4 + m) * 16 + lr;
      bf16x8 ahi = *(const bf16x8*)&Wp[o * 64 + ((lg ^ (o & 7)) * 8)];
      bf16x8 alo = *(const bf16x8*)&Wp[o * 64 + (((4 + lg) ^ (o & 7)) * 8)];
      #pragma unroll
      for (int n = 0; n < 4; n++) {
        acc[m][n] = __builtin_amdgcn_mfma_f32_16x16x32_bf16(ahi, bfr[n], acc[m][n], 0, 0, 0);
        acc[m][n] = __builtin_amdgcn_mfma_f32_16x16x32_bf16(alo, bfr[n], acc[m][n], 0, 0, 0);
      }
    }
    __syncthreads();
  }

  // ---- epilogue via LDS round-trip for vectorized global stores ----
  if (FINAL) {
    float* Otf = (float*)S;             // [256 o][64 px] f32, swizzled
    #pragma unroll
    for (int m = 0; m < 4; m++)
      #pragma unroll
      for (int r = 0; r < 4; r++) {
        int o = (wid * 4 + m) * 16 + 4 * lg + r;
        float bv = 2.f * bias[o];
        #pragma unroll
        for (int n = 0; n < 4; n++) {
          int px = n * 16 + lr;
          Otf[o * 64 + (px ^ ((o & 7) * 8))] = acc[m][n][r] + bv;
        }
      }
    __syncthreads();
    int f = getf(fh, flagp);
    size_t gbase = ((size_t)bl * NC + t) * NHW + p0;
    #pragma unroll
    for (int j2 = 0; j2 < 16; j2++) {
      float4 v = *(float4*)&Otf[t * 64 + ((j2 * 4) ^ ((t & 7) * 8))];
      size_t gi = gbase + j2 * 4;
      if (f) {
        const float* xp = (const float*)xsrc + xoff + gi;
        v.x += xp[0]; v.y += xp[1]; v.z += xp[2]; v.w += xp[3];
        *(float4*)((float*)OutBase + out_off + gi) = v;
      } else {
        ushort4 xv = *(const ushort4*)((const u16*)xsrc + xoff + gi);
        ushort4 ov;
        ov.x = f2b(v.x + b2f(xv.x)); ov.y = f2b(v.y + b2f(xv.y));
        ov.z = f2b(v.z + b2f(xv.z)); ov.w = f2b(v.w + b2f(xv.w));
        *(ushort4*)((u16*)OutBase + out_off + gi) = ov;
      }
    }
  } else {
    u16* Ot = S;                        // [256 o][64 px] u16, swizzled
    #pragma unroll
    for (int m = 0; m < 4; m++)
      #pragma unroll
      for (int r = 0; r < 4; r++) {
        int o = (wid * 4 + m) * 16 + 4 * lg + r;
        float bv = bias[o];
        #pragma unroll
        for (int n = 0; n < 4; n++) {
          int px = n * 16 + lr;
          Ot[o * 64 + (px ^ ((o & 7) * 8))] = f2b(acc[m][n][r] + bv);
        }
      }
    __syncthreads();
    u16* orow = io + ((size_t)bl * NC + t) * NHW + p0;
    #pragma unroll
    for (int j = 0; j < 8; j++) {
      uint4 v = *(uint4*)&Ot[t * 64 + ((j ^ (t & 7)) * 8)];
      *(uint4*)(orow + j * 8) = v;
    }
  }
  (void)OutBase; (void)out_off; (void)xsrc; (void)xoff; (void)flagp; (void)io1;
}

// ---- K-T fused: per-plane 80x80 bf16 transpose + row/col sum of squares ----
__global__ __launch_bounds__(256) void transpose_sumsq(const u16* __restrict__ fx,
    const u16* __restrict__ fy, u16* __restrict__ fxT, u16* __restrict__ fyT,
    float* __restrict__ rs_fx, float* __restrict__ rs_fy,
    float* __restrict__ cs_fx, float* __restrict__ cs_fy)
{
  __shared__ u16 tile[80][81];
  int pl = blockIdx.x, ten = blockIdx.y;
  const u16* src = (ten ? fy : fx) + (size_t)pl * NHW;
  u16*       dst = (ten ? fyT : fxT) + (size_t)pl * NHW;
  int t = threadIdx.x;
  for (int i = t; i < NHW; i += 256) tile[i / 80][i % 80] = src[i];
  __syncthreads();
  for (int i = t; i < NHW; i += 256) dst[i] = tile[i % 80][i / 80];
  if (t < 80) {
    float s = 0.f;
    #pragma unroll
    for (int k = 0; k < 80; k++) { float v = b2f(tile[t][k]); s += v * v; }
    (ten ? rs_fy : rs_fx)[pl * 80 + t] = s;
  } else if (t < 160) {
    int w = t - 80; float s = 0.f;
    #pragma unroll
    for (int h = 0; h < 80; h++) { float v = b2f(tile[h][w]); s += v * v; }
    (ten ? cs_fy : cs_fx)[pl * 80 + w] = s;
  }
}

// ---- K5: combine over ci -> inverse norms ----
__global__ __launch_bounds__(256) void norm_combine(const float* __restrict__ rs_fx,
    const float* __restrict__ rs_fy, const float* __restrict__ cs_fx,
    const float* __restrict__ cs_fy, float* __restrict__ invn, int Nb)
{
  int t = blockIdx.x * 256 + threadIdx.x;   // 4*Nb*640 total
  int blk = Nb * 640;
  int side = t / blk, r = t % blk;
  int b = r / 640, rem = r % 640, hd = rem / 80, row = rem % 80;
  const float* src = (side == 0) ? rs_fy : (side == 1) ? rs_fx : (side == 2) ? cs_fx : cs_fy;
  size_t base = (size_t)(b * 256 + hd * 32) * 80 + row;
  float s = 0.f;
  #pragma unroll
  for (int ci = 0; ci < 32; ci++) s += src[base + ci * 80];
  invn[t] = 1.f / fmaxf(sqrtf(s), 1e-12f);
}

// ---- MFMA helpers for 80x80 Gram-style tiles ----
template<int T0, int NT>
__device__ __forceinline__ void gram_wave(const u16* pa, const u16* pb,
                                          int lg, int lr, f32x4* acc)
{
  constexpr int MLO = T0 / 5;
  #pragma unroll
  for (int ch = 0; ch < 3; ch++) {
    bool tz = (ch == 2) && (lg >= 2);
    int kk = ch * 32 + 8 * lg;
    if (tz) kk = 0;
    bf16x8 af[2], bf[5];
    #pragma unroll
    for (int m = 0; m < 2; m++)
      af[m] = *(const bf16x8*)(pa + ((MLO + m) * 16 + lr) * 80 + kk);
    #pragma unroll
    for (int n = 0; n < 5; n++)
      bf[n] = *(const bf16x8*)(pb + (n * 16 + lr) * 80 + kk);
    if (tz) {
      bf16x8 z = {0, 0, 0, 0, 0, 0, 0, 0};
      af[0] = z; af[1] = z;
    }
    #pragma unroll
    for (int j = 0; j < NT; j++) {
      acc[j] = __builtin_amdgcn_mfma_f32_16x16x32_bf16(
          af[(T0 + j) / 5 - MLO], bf[(T0 + j) % 5], acc[j], 0, 0, 0);
    }
  }
}

template<int T0, int NT>
__device__ __forceinline__ void gram_all(const u16* Ab, const u16* Bb,
                                         int lg, int lr, f32x4* acc)
{
  for (int ci = 0; ci < 32; ci++)
    gram_wave<T0, NT>(Ab + (size_t)ci * NHW, Bb + (size_t)ci * NHW, lg, lr, acc);
}

// ---- K6: MFMA Gram (sum over 32 ci) + cosine scale + softmax -> Sbuf ----
__global__ __launch_bounds__(256) void gram_softmax_mfma(const u16* __restrict__ fx,
    const u16* __restrict__ fy, const u16* __restrict__ fxT, const u16* __restrict__ fyT,
    const float* __restrict__ invn, u16* __restrict__ Sbuf, int Nb)
{
  __shared__ float At[80][81];
  int hd = blockIdx.x, b = blockIdx.y, axis = blockIdx.z;
  size_t sl0 = (size_t)(b * 256 + hd * 32) * NHW;
  const u16* Ab = (axis ? fxT : fy) + sl0;
  const u16* Bb = (axis ? fyT : fx) + sl0;
  int t = threadIdx.x, lane = t & 63, wid = t >> 6;
  int lg = lane >> 4, lr = lane & 15;
  f32x4 acc0 = {0.f, 0.f, 0.f, 0.f};
  f32x4 acc[7];
  #pragma unroll
  for (int j = 0; j < 7; j++) acc[j] = acc0;
  if      (wid == 0) gram_all<0, 7>(Ab, Bb, lg, lr, acc);
  else if (wid == 1) gram_all<7, 6>(Ab, Bb, lg, lr, acc);
  else if (wid == 2) gram_all<13, 6>(Ab, Bb, lg, lr, acc);
  else               gram_all<19, 6>(Ab, Bb, lg, lr, acc);
  int blk = Nb * 640;
  int rowbase = (b * 8 + hd) * 80;
  const float* invq = invn + (axis ? 2 * blk : 0)   + rowbase;
  const float* invk = invn + (axis ? 3 * blk : blk) + rowbase;
  int t0  = wid ? 6 * wid + 1 : 0;
  int cnt = wid ? 6 : 7;
  #pragma unroll
  for (int j = 0; j < 7; j++) {
    if (j < cnt) {
      int tt = t0 + j, m = tt / 5, n = tt % 5;
      int col = n * 16 + lr;
      float ik = invk[col];
      #pragma unroll
      for (int r = 0; r < 4; r++) {
        int row = m * 16 + 4 * lg + r;
        float gv = acc[j][r] * invq[row] * ik;
        At[row][col] = fminf(fmaxf(gv, -8.f), 8.f);  // |cos|<=1; NaN->-8
      }
    }
  }
  __syncthreads();
  u16* Sg = Sbuf + ((size_t)(axis * Nb * 8 + b * 8 + hd)) * NHW;
  if (t < 80) {
    float mx = -1e30f;
    for (int j = 0; j < 80; j++) mx = fmaxf(mx, At[t][j]);
    float s = 0.f;
    for (int j = 0; j < 80; j++) s += __expf(At[t][j] - mx);
    float inv = 1.f / s;
    for (int j = 0; j < 80; j++) Sg[t * 80 + j] = f2b(__expf(At[t][j] - mx) * inv);
  }
}

// ---- K7: MFMA fused H+W attention apply, IN PLACE over fx slice ----
template<int T0, int NT>
__device__ __forceinline__ void apply_wave(const u16* SH, const u16* fxT,
    const u16* fyP, const u16* SW, int lg, int lr, f32x4* acc)
{
  constexpr int MLO = T0 / 5;
  for (int ch = 0; ch < 3; ch++) {
    bool tz = (ch == 2) && (lg >= 2);
    int kk = ch * 32 + 8 * lg;
    if (tz) kk = 0;
    bf16x8 a1[2], a2[2], b1[5], b2[5];
    #pragma unroll
    for (int m = 0; m < 2; m++) {
      a1[m] = *(const bf16x8*)(SH  + ((MLO + m) * 16 + lr) * 80 + kk);
      a2[m] = *(const bf16x8*)(fyP + ((MLO + m) * 16 + lr) * 80 + kk);
    }
    #pragma unroll
    for (int n = 0; n < 5; n++) {
      b1[n] = *(const bf16x8*)(fxT + (n * 16 + lr) * 80 + kk);
      b2[n] = *(const bf16x8*)(SW  + (n * 16 + lr) * 80 + kk);
    }
    if (tz) {
      bf16x8 z = {0, 0, 0, 0, 0, 0, 0, 0};
      a1[0] = z; a1[1] = z; a2[0] = z; a2[1] = z;
    }
    #pragma unroll
    for (int j = 0; j < NT; j++) {
      acc[j] = __builtin_amdgcn_mfma_f32_16x16x32_bf16(
          a1[(T0 + j) / 5 - MLO], b1[(T0 + j) % 5], acc[j], 0, 0, 0);
      acc[j] = __builtin_amdgcn_mfma_f32_16x16x32_bf16(
          a2[(T0 + j) / 5 - MLO], b2[(T0 + j) % 5], acc[j], 0, 0, 0);
    }
  }
}

__global__ __launch_bounds__(256, 2) void apply_hw_mfma(const u16* __restrict__ fy_g,
    const u16* __restrict__ fxT_g, const u16* __restrict__ Sbuf,
    const float* __restrict__ invn, u16* fx_io, int Nb)
{
  int ci = blockIdx.x, hd = blockIdx.y, b = blockIdx.z;
  size_t off = (size_t)(b * 256 + hd * 32 + ci) * NHW;
  const u16* SgH = Sbuf + (size_t)(b * 8 + hd) * NHW;
  const u16* SgW = Sbuf + ((size_t)(Nb * 8) + b * 8 + hd) * NHW;
  const u16* fyP = fy_g + off;
  const u16* fxT = fxT_g + off;
  int t = threadIdx.x, lane = t & 63, wid = t >> 6;
  int lg = lane >> 4, lr = lane & 15;
  f32x4 acc0 = {0.f, 0.f, 0.f, 0.f};
  f32x4 acc[7];
  #pragma unroll
  for (int j = 0; j < 7; j++) acc[j] = acc0;
  if      (wid == 0) apply_wave<0, 7>(SgH, fxT, fyP, SgW, lg, lr, acc);
  else if (wid == 1) apply_wave<7, 6>(SgH, fxT, fyP, SgW, lg, lr, acc);
  else if (wid == 2) apply_wave<13, 6>(SgH, fxT, fyP, SgW, lg, lr, acc);
  else               apply_wave<19, 6>(SgH, fxT, fyP, SgW, lg, lr, acc);
  const float* invqH = invn + (b * 8 + hd) * 80;                 // H_fy(q)
  const float* invqW = invn + 2 * Nb * 640 + (b * 8 + hd) * 80;  // W_fx(q)
  int t0  = wid ? 6 * wid + 1 : 0;
  int cnt = wid ? 6 : 7;
  #pragma unroll
  for (int j = 0; j < 7; j++) {
    if (j < cnt) {
      int tt = t0 + j, m = tt / 5, n = tt % 5;
      int col = n * 16 + lr;
      float ivW = invqW[col];
      #pragma unroll
      for (int r = 0; r < 4; r++) {
        int row = m * 16 + 4 * lg + r;
        size_t ix = off + row * 80 + col;
        float v = acc[j][r] + b2f(fy_g[ix]) * invqH[row] + b2f(fx_io[ix]) * ivW;
        fx_io[ix] = f2b(v);
      }
    }
  }
}

extern "C" void kernel_launch(void* const* d_in, const int* in_sizes, int n_in,
                              void* d_out, int out_size, void* d_ws, size_t ws_size,
                              hipStream_t stream) {
  // Weight conversion table: d_in[1..18] in setup_inputs order.
  const int wsz[18] = {256, 256, 65536, 256, 65536, 256,
                       1792, 256, 2816, 256, 5376, 256,
                       1792, 256, 2816, 256, 5376, 256};
  CvtArgs ca;
  int cum = 0;
  for (int i = 0; i < 18; i++) { ca.src[i] = d_in[i + 1]; ca.cum[i] = cum; cum += wsz[i]; }
  ca.cum[18] = cum;   // 153600

  // Host-side dtype detection: x (and out) have 26,214,400 elements, so
  // 104857600 bytes => f32, 52428800 => bf16. Try in_sizes[0] AND out_size.
  // Fall back to the fast device probe only if neither matches.
  int hostf = -1;
  if (in_sizes && n_in > 0) {
    if      (in_sizes[0] == 104857600) hostf = 1;
    else if (in_sizes[0] == 52428800)  hostf = 0;
  }
  if (hostf < 0) {
    if      (out_size == 104857600) hostf = 1;
    else if (out_size == 52428800)  hostf = 0;
  }

  // ws layout: flag(16) | wbuf(614400) | wsplit(524288) | per-chunk buffers.
  int Nb = 1;
  for (int cand = 16; cand >= 1; cand >>= 1) {
    size_t need = (size_t)cand * 13701120 + 614416 + 524288;
    if (need <= ws_size) { Nb = cand; break; }
  }
  char* p = (char*)d_ws;
  int*    flag  = (int*)p;    p += 16;
  float*  wbuf  = (float*)p;  p += 614400;
  u16*    wsplit= (u16*)p;    p += 524288;     // [2 mat][2 set][256][256] bf16
  u16*    fxbuf = (u16*)p;    p += (size_t)Nb * 3276800;
  u16*    fybuf = (u16*)p;    p += (size_t)Nb * 3276800;
  u16*    fxT   = (u16*)p;    p += (size_t)Nb * 3276800;
  u16*    fyT   = (u16*)p;    p += (size_t)Nb * 3276800;
  float2* stats = (float2*)p; p += (size_t)Nb * 51200;
  float*  rs_fx = (float*)p;  p += (size_t)Nb * 81920;
  float*  rs_fy = (float*)p;  p += (size_t)Nb * 81920;
  float*  cs_fx = (float*)p;  p += (size_t)Nb * 81920;
  float*  cs_fy = (float*)p;  p += (size_t)Nb * 81920;
  float*  invn  = (float*)p;  p += (size_t)Nb * 10240;
  u16*    Sbuf  = (u16*)p;

  // f32 weight views
  float* ln_g = wbuf + ca.cum[0];  float* ln_b = wbuf + ca.cum[1];
  float* w_in = wbuf + ca.cum[2];  float* b_in = wbuf + ca.cum[3];
  float* w_out= wbuf + ca.cum[4]; float* b_out= wbuf + ca.cum[5];
  float* wx7  = wbuf + ca.cum[6];  float* bx7  = wbuf + ca.cum[7];
  float* wx11 = wbuf + ca.cum[8];  float* bx11 = wbuf + ca.cum[9];
  float* wx21 = wbuf + ca.cum[10]; float* bx21 = wbuf + ca.cum[11];
  float* wy7  = wbuf + ca.cum[12]; float* by7  = wbuf + ca.cum[13];
  float* wy11 = wbuf + ca.cum[14]; float* by11 = wbuf + ca.cum[15];
  float* wy21 = wbuf + ca.cum[16]; float* by21 = wbuf + ca.cum[17];

  if (hostf < 0) {
    probe_init<<<dim3(1), dim3(1), 0, stream>>>(flag);
    probe_count<<<dim3(64), dim3(256), 0, stream>>>((const u16*)d_in[0], flag);
    probe_decide<<<dim3(1), dim3(1), 0, stream>>>(flag);
  }
  cvt_weights<<<dim3(600), dim3(256), 0, stream>>>(ca, wbuf, hostf, flag);
  split_w<<<dim3(512), dim3(256), 0, stream>>>(w_in, w_out, wsplit);

  for (int b0 = 0; b0 < NB; b0 += Nb) {
    size_t xoff = (size_t)b0 * NC * NHW;   // element offset of chunk in x / out

    ln_stats<<<dim3(Nb * 25), dim3(256), 0, stream>>>(d_in[0], xoff, hostf, flag, stats);
    dw_both<<<dim3(Nb * 256), dim3(256), 0, stream>>>(d_in[0], xoff, hostf, flag, stats,
        ln_g, ln_b, wx7, bx7, wx11, bx11, wx21, bx21,
        wy7, by7, wy11, by11, wy21, by21, fxbuf, fybuf);
    pw_mfma_t<0><<<dim3(100, Nb, 2), dim3(256), 0, stream>>>(wsplit, fxbuf, fybuf,
        b_in, nullptr, 0, nullptr, 0, hostf, flag);
    transpose_sumsq<<<dim3(Nb * 256, 2), dim3(256), 0, stream>>>(fxbuf, fybuf, fxT, fyT,
        rs_fx, rs_fy, cs_fx, cs_fy);
    norm_combine<<<dim3(10 * Nb), dim3(256), 0, stream>>>(rs_fx, rs_fy, cs_fx, cs_fy, invn, Nb);
    gram_softmax_mfma<<<dim3(8, Nb, 2), dim3(256), 0, stream>>>(fxbuf, fybuf, fxT, fyT, invn, Sbuf, Nb);
    apply_hw_mfma<<<dim3(32, 8, Nb), dim3(256), 0, stream>>>(fybuf, fxT, Sbuf, invn, fxbuf, Nb);
    pw_mfma_t<1><<<dim3(100, Nb, 1), dim3(256), 0, stream>>>(wsplit + 131072, fxbuf, nullptr,
        b_out, d_out, xoff, d_in[0], xoff, hostf, flag);
  }
  (void)in_sizes; (void)n_in; (void)out_size;
}

// Round 5
// 860.323 us; speedup vs baseline: 2.2011x; 1.1082x over previous
//
#include <hip/hip_runtime.h>

typedef unsigned short u16;
typedef unsigned int   u32;

#define NB  16
#define NC  256
#define NH  80
#define NW  80
#define NHW 6400

typedef short bf16x8 __attribute__((ext_vector_type(8)));
typedef float f32x4  __attribute__((ext_vector_type(4)));

__device__ __forceinline__ float b2f(u16 u) {
  union { u32 i; float f; } c; c.i = ((u32)u) << 16; return c.f;
}
__device__ __forceinline__ u16 f2b(float f) {
  union { float f; u32 i; } c; c.f = f;
  return (u16)((c.i + 0x7FFFu + ((c.i >> 16) & 1u)) >> 16);
}
// dtype-dispatched input load (flag=1: f32, flag=0: bf16)
__device__ __forceinline__ float ldx(const void* p, size_t i, int f32f) {
  return f32f ? ((const float*)p)[i] : b2f(((const u16*)p)[i]);
}
// resolve dtype flag: host-decided (fh>=0) or device-probed fallback
__device__ __forceinline__ int getf(int fh, const int* flagp) {
  return (fh >= 0) ? fh : *flagp;
}

// ---- K0a (fallback only): fast parallel dtype probe ----
__global__ void probe_init(int* __restrict__ flag) { flag[0] = 0; flag[1] = 0; }

__global__ __launch_bounds__(256) void probe_count(const u16* __restrict__ x,
                                                   int* __restrict__ flag)
{
  __shared__ int cnt[256];
  int base = (blockIdx.x * 256 + threadIdx.x) * 16;   // 64*256*16 = 262144
  int c = 0;
  uint4 v0 = *(const uint4*)(x + base);
  uint4 v1 = *(const uint4*)(x + base + 8);
  u32 w[8] = {v0.x, v0.y, v0.z, v0.w, v1.x, v1.y, v1.z, v1.w};
  #pragma unroll
  for (int j = 0; j < 8; j++) {
    if (((w[j] >> 7)  & 0xFFu) == 0xFFu) c++;
    if (((w[j] >> 23) & 0xFFu) == 0xFFu) c++;
  }
  cnt[threadIdx.x] = c; __syncthreads();
  for (int s = 128; s > 0; s >>= 1) {
    if (threadIdx.x < s) cnt[threadIdx.x] += cnt[threadIdx.x + s];
    __syncthreads();
  }
  if (threadIdx.x == 0) atomicAdd(&flag[1], cnt[0]);
}

__global__ void probe_decide(int* __restrict__ flag) {
  flag[0] = (flag[1] > 16) ? 1 : 0;
}

// ---- K0b: convert all 18 weight/bias arrays into one f32 table ----
struct CvtArgs { const void* src[18]; int cum[19]; };

__global__ __launch_bounds__(256) void cvt_weights(CvtArgs a, float* __restrict__ dst,
                                                   int fh, const int* __restrict__ flagp)
{
  int f = getf(fh, flagp);
  int i = blockIdx.x * 256 + threadIdx.x;     // < 153600
  int s = 0;
  while (i >= a.cum[s + 1]) s++;
  int j = i - a.cum[s];
  float v = f ? ((const float*)a.src[s])[j] : b2f(((const u16*)a.src[s])[j]);
  if (!(v == v) || fabsf(v) > 1e30f) v = 0.f;  // scrub
  dst[i] = v;
}

// ---- K0c: split w_in / w_out into bf16 hi+lo pairs for MFMA.
// WB layout: [mat][set][256 o][256 k] u16, mat stride 131072, set stride 65536.
__global__ __launch_bounds__(256) void split_w(const float* __restrict__ w_in,
    const float* __restrict__ w_out, u16* __restrict__ WB)
{
  int i = blockIdx.x * 256 + threadIdx.x;   // < 131072
  int mat = i >> 16, idx = i & 65535;
  float v = (mat ? w_out : w_in)[idx];
  u16 hi = f2b(v);
  u16 lo = f2b(v - b2f(hi));
  WB[mat * 131072 + idx] = hi;
  WB[mat * 131072 + 65536 + idx] = lo;
}

// ---- K1: per-pixel LN stats (mean, rstd) over C; 4 px/thread vectorized ----
__global__ __launch_bounds__(256) void ln_stats(const void* __restrict__ xsrc,
    size_t xoff, int fh, const int* __restrict__ flagp, float2* __restrict__ stats)
{
  int f = getf(fh, flagp);
  int bl = blockIdx.y;
  int p4 = blockIdx.x * 1024 + threadIdx.x * 4;
  if (p4 >= NHW) return;                       // last block covers 256 px only
  size_t base = xoff + (size_t)bl * NC * NHW + p4;
  float s1[4] = {0.f, 0.f, 0.f, 0.f}, s2[4] = {0.f, 0.f, 0.f, 0.f};
  if (f) {
    const float* xp = (const float*)xsrc + base;
    for (int c = 0; c < NC; c++) {
      float4 v = *(const float4*)(xp + (size_t)c * NHW);
      s1[0] += v.x; s2[0] += v.x * v.x;
      s1[1] += v.y; s2[1] += v.y * v.y;
      s1[2] += v.z; s2[2] += v.z * v.z;
      s1[3] += v.w; s2[3] += v.w * v.w;
    }
  } else {
    const u16* xp = (const u16*)xsrc + base;
    for (int c = 0; c < NC; c++) {
      ushort4 v = *(const ushort4*)(xp + (size_t)c * NHW);
      float a = b2f(v.x), b = b2f(v.y), cc = b2f(v.z), d = b2f(v.w);
      s1[0] += a;  s2[0] += a * a;
      s1[1] += b;  s2[1] += b * b;
      s1[2] += cc; s2[2] += cc * cc;
      s1[3] += d;  s2[3] += d * d;
    }
  }
  float2* so = stats + (size_t)bl * NHW + p4;
  #pragma unroll
  for (int j = 0; j < 4; j++) {
    float mean = s1[j] * (1.f / 256.f);
    float var  = s2[j] * (1.f / 256.f) - mean * mean;
    so[j] = make_float2(mean, rsqrtf(var + 1e-5f));
  }
}

// ---- K2: fused LN + BOTH depthwise convs, register-blocked stencil.
// Each thread owns 8-px row segments (800 units/block). Plane in LDS with
// 16-col zero halos, row stride 116 (=20 mod 32 -> cross-row bank spread).
// Horizontal taps come from a 32-float register window (8x ds_read_b128);
// vertical taps from 2x ds_read_b128 per tap serving all 8 px. Row bounds via
// clamp + weight-select-0 (adds exact 0 => bit-identical to branch skip). ----
__global__ __launch_bounds__(256) void dw_both(const void* __restrict__ xsrc,
    size_t xoff, int fh, const int* __restrict__ flagp,
    const float2* __restrict__ stats,
    const float* __restrict__ g, const float* __restrict__ bt,
    const float* __restrict__ wx7,  const float* __restrict__ bx7,
    const float* __restrict__ wx11, const float* __restrict__ bx11,
    const float* __restrict__ wx21, const float* __restrict__ bx21,
    const float* __restrict__ wy7,  const float* __restrict__ by7,
    const float* __restrict__ wy11, const float* __restrict__ by11,
    const float* __restrict__ wy21, const float* __restrict__ by21,
    u16* __restrict__ sx, u16* __restrict__ sy)
{
  __shared__ float xnp[80][116];        // cols 0..15 & 96..111 zero halo
  __shared__ float cwx[21], cwy[21];
  __shared__ float cbs[2];
  int f = getf(fh, flagp);
  int bc = blockIdx.x;                  // bl*256 + c
  int c  = bc & 255;
  int bl = bc >> 8;
  int t = threadIdx.x;
  if (t < 21) {
    float v = wx21[c * 21 + t];
    if (t >= 5 && t <= 15) v += wx11[c * 11 + t - 5];
    if (t >= 7 && t <= 13) v += wx7[c * 7 + t - 7];
    cwx[t] = v;
  } else if (t < 42) {
    int j = t - 21;
    float v = wy21[c * 21 + j];
    if (j >= 5 && j <= 15) v += wy11[c * 11 + j - 5];
    if (j >= 7 && j <= 13) v += wy7[c * 7 + j - 7];
    cwy[j] = v;
  } else if (t == 42) { cbs[0] = bx7[c] + bx11[c] + bx21[c]; }
  else if (t == 43)   { cbs[1] = by7[c] + by11[c] + by21[c]; }
  // zero halo columns (80 rows x 32 cols)
  for (int i = t; i < 2560; i += 256) {
    int rr = i >> 5, cc = i & 31;
    xnp[rr][cc < 16 ? cc : 80 + cc] = 0.f;
  }
  float cg = g[c], cbt = bt[c];
  size_t xrow = xoff + (size_t)bc * NHW;
  const float2* st = stats + (size_t)bl * NHW;
  for (int i = t; i < NHW; i += 256) {
    float v = ldx(xsrc, xrow + i, f);
    float2 s = st[i];
    xnp[i / 80][16 + i % 80] = (v - s.x) * s.y * cg + cbt;
  }
  __syncthreads();
  float bxv = cbs[0], byv = cbs[1];
  size_t obase = (size_t)bc * NHW;
  for (int u = t; u < 800; u += 256) {  // 3 full rounds + 32-thread tail
    int h = u / 10, w0 = (u % 10) * 8;
    float r[32];
    #pragma unroll
    for (int j = 0; j < 8; j++)
      *(float4*)&r[4 * j] = *(const float4*)&xnp[h][w0 + 4 + 4 * j];
    float ax[8], ay[8];
    #pragma unroll
    for (int j = 0; j < 8; j++) { ax[j] = bxv; ay[j] = byv; }
    #pragma unroll
    for (int dd = 0; dd < 21; dd++) {
      float wv = cwx[dd];
      #pragma unroll
      for (int j = 0; j < 8; j++) ax[j] += wv * r[j + 2 + dd];
    }
    #pragma unroll
    for (int dd = 0; dd < 21; dd++) {
      int hp = h + dd - 10;
      int hc = min(max(hp, 0), 79);
      float wv = (hp == hc) ? cwy[dd] : 0.f;
      float4 v0 = *(const float4*)&xnp[hc][16 + w0];
      float4 v1 = *(const float4*)&xnp[hc][20 + w0];
      ay[0] += wv * v0.x; ay[1] += wv * v0.y; ay[2] += wv * v0.z; ay[3] += wv * v0.w;
      ay[4] += wv * v1.x; ay[5] += wv * v1.y; ay[6] += wv * v1.z; ay[7] += wv * v1.w;
    }
    size_t ob = obase + h * 80 + w0;
    ushort4 a0, a1, b0, b1;
    a0.x = f2b(ax[0]); a0.y = f2b(ax[1]); a0.z = f2b(ax[2]); a0.w = f2b(ax[3]);
    a1.x = f2b(ax[4]); a1.y = f2b(ax[5]); a1.z = f2b(ax[6]); a1.w = f2b(ax[7]);
    b0.x = f2b(ay[0]); b0.y = f2b(ay[1]); b0.z = f2b(ay[2]); b0.w = f2b(ay[3]);
    b1.x = f2b(ay[4]); b1.y = f2b(ay[5]); b1.z = f2b(ay[6]); b1.w = f2b(ay[7]);
    *(ushort4*)(sx + ob)     = a0;
    *(ushort4*)(sx + ob + 4) = a1;
    *(ushort4*)(sy + ob)     = b0;
    *(ushort4*)(sy + ob + 4) = b1;
  }
}

// ---- K3/K8: MFMA pointwise conv. C[o][p] = sum_k W[o][k]*In[k][p], W split
// into bf16 hi+lo. One block = full 256 o x 64 px strip of one batch.
// FINAL=1: out = acc + 2*bias + x, dtype-dispatched; else in-place bf16 + bias.
template<int FINAL>
__global__ __launch_bounds__(256) void pw_mfma_t(const u16* __restrict__ WB,
    u16* io0, u16* io1, const float* __restrict__ bias,
    void* __restrict__ OutBase, size_t out_off,
    const void* __restrict__ xsrc, size_t xoff,
    int fh, const int* __restrict__ flagp)
{
  __shared__ u16 S[32768];              // 64 KB: InT = S[0:16384], Wp = S[16384:]
  u16* InT = S;
  u16* Wp  = S + 16384;
  int bl = blockIdx.y;
  int p0 = blockIdx.x * 64;
  int t  = threadIdx.x;
  int lane = t & 63, wid = t >> 6, lg = lane >> 4, lr = lane & 15;
  u16* io = (FINAL || blockIdx.z == 0) ? io0 : io1;

  // ---- stage InT with register 8x8 transpose; swizzle col8 ^= (px&7) ----
  {
    int kb = t >> 3, pb = t & 7;
    const u16* src = io + (size_t)bl * NC * NHW + p0 + pb * 8;
    u32 r[8][4];
    #pragma unroll
    for (int i = 0; i < 8; i++) {
      uint4 v = *(const uint4*)(src + (size_t)(kb * 8 + i) * NHW);
      r[i][0] = v.x; r[i][1] = v.y; r[i][2] = v.z; r[i][3] = v.w;
    }
    #pragma unroll
    for (int j = 0; j < 8; j++) {
      u32 w[4];
      #pragma unroll
      for (int m = 0; m < 4; m++) {
        u32 a = r[2 * m][j >> 1], b = r[2 * m + 1][j >> 1];
        w[m] = (j & 1) ? ((a >> 16) | (b & 0xFFFF0000u))
                       : ((a & 0xFFFFu) | (b << 16));
      }
      int p = pb * 8 + j;
      *(uint4*)&InT[p * 256 + ((kb ^ j) * 8)] = make_uint4(w[0], w[1], w[2], w[3]);
    }
  }
  __syncthreads();

  f32x4 acc[4][4];
  #pragma unroll
  for (int m = 0; m < 4; m++)
    #pragma unroll
    for (int n = 0; n < 4; n++)
      acc[m][n] = (f32x4){0.f, 0.f, 0.f, 0.f};

  for (int ch = 0; ch < 8; ch++) {
    // stage W panel (hi unit 0..3 | lo unit 4..7) for k = ch*32..+31
    #pragma unroll
    for (int rep = 0; rep < 8; rep++) {
      int o = rep * 32 + (t >> 3), sg = t & 7;
      uint4 v = *(const uint4*)(WB + (sg >> 2) * 65536 + o * 256 + ch * 32 + (sg & 3) * 8);
      *(uint4*)&Wp[o * 64 + ((sg ^ (o & 7)) * 8)] = v;
    }
    __syncthreads();
    bf16x8 bfr[4];
    #pragma unroll
    for (int n = 0; n < 4; n++) {
      int px = n * 16 + lr;
      bfr[n] = *(const bf16x8*)&InT[px * 256 + (((ch * 4 + lg) ^ (px & 7)) * 8)];
    }
    #pragma unroll
    for (int m = 0; m < 4; m++) {
      int o = (wid * 4 + m) * 16 + lr;
      bf16x8 ahi = *(const bf16x8*)&Wp[o * 64 + ((lg ^ (o & 7)) * 8)];
      bf16x8 alo = *(const bf16x8*)&Wp[o * 64 + (((4 + lg) ^ (o & 7)) * 8)];
      #pragma unroll
      for (int n = 0; n < 4; n++) {
        acc[m][n] = __builtin_amdgcn_mfma_f32_16x16x32_bf16(ahi, bfr[n], acc[m][n], 0, 0, 0);
        acc[m][n] = __builtin_amdgcn_mfma_f32_16x16x32_bf16(alo, bfr[n], acc[m][n], 0, 0, 0);
      }
    }
    __syncthreads();
  }

  // ---- epilogue via LDS round-trip for vectorized global stores ----
  if (FINAL) {
    float* Otf = (float*)S;             // [256 o][64 px] f32, swizzled
    #pragma unroll
    for (int m = 0; m < 4; m++)
      #pragma unroll
      for (int r = 0; r < 4; r++) {
        int o = (wid * 4 + m) * 16 + 4 * lg + r;
        float bv = 2.f * bias[o];
        #pragma unroll
        for (int n = 0; n < 4; n++) {
          int px = n * 16 + lr;
          Otf[o * 64 + (px ^ ((o & 7) * 8))] = acc[m][n][r] + bv;
        }
      }
    __syncthreads();
    int f = getf(fh, flagp);
    size_t gbase = ((size_t)bl * NC + t) * NHW + p0;
    #pragma unroll
    for (int j2 = 0; j2 < 16; j2++) {
      float4 v = *(float4*)&Otf[t * 64 + ((j2 * 4) ^ ((t & 7) * 8))];
      size_t gi = gbase + j2 * 4;
      if (f) {
        const float* xp = (const float*)xsrc + xoff + gi;
        v.x += xp[0]; v.y += xp[1]; v.z += xp[2]; v.w += xp[3];
        *(float4*)((float*)OutBase + out_off + gi) = v;
      } else {
        ushort4 xv = *(const ushort4*)((const u16*)xsrc + xoff + gi);
        ushort4 ov;
        ov.x = f2b(v.x + b2f(xv.x)); ov.y = f2b(v.y + b2f(xv.y));
        ov.z = f2b(v.z + b2f(xv.z)); ov.w = f2b(v.w + b2f(xv.w));
        *(ushort4*)((u16*)OutBase + out_off + gi) = ov;
      }
    }
  } else {
    u16* Ot = S;                        // [256 o][64 px] u16, swizzled
    #pragma unroll
    for (int m = 0; m < 4; m++)
      #pragma unroll
      for (int r = 0; r < 4; r++) {
        int o = (wid * 4 + m) * 16 + 4 * lg + r;
        float bv = bias[o];
        #pragma unroll
        for (int n = 0; n < 4; n++) {
          int px = n * 16 + lr;
          Ot[o * 64 + (px ^ ((o & 7) * 8))] = f2b(acc[m][n][r] + bv);
        }
      }
    __syncthreads();
    u16* orow = io + ((size_t)bl * NC + t) * NHW + p0;
    #pragma unroll
    for (int j = 0; j < 8; j++) {
      uint4 v = *(uint4*)&Ot[t * 64 + ((j ^ (t & 7)) * 8)];
      *(uint4*)(orow + j * 8) = v;
    }
  }
  (void)OutBase; (void)out_off; (void)xsrc; (void)xoff; (void)flagp; (void)io1;
}

// ---- K-T fused: per-plane 80x80 bf16 transpose + row/col sum of squares ----
__global__ __launch_bounds__(256) void transpose_sumsq(const u16* __restrict__ fx,
    const u16* __restrict__ fy, u16* __restrict__ fxT, u16* __restrict__ fyT,
    float* __restrict__ rs_fx, float* __restrict__ rs_fy,
    float* __restrict__ cs_fx, float* __restrict__ cs_fy)
{
  __shared__ u16 tile[80][81];
  int pl = blockIdx.x, ten = blockIdx.y;
  const u16* src = (ten ? fy : fx) + (size_t)pl * NHW;
  u16*       dst = (ten ? fyT : fxT) + (size_t)pl * NHW;
  int t = threadIdx.x;
  for (int i = t; i < NHW; i += 256) tile[i / 80][i % 80] = src[i];
  __syncthreads();
  for (int i = t; i < NHW; i += 256) dst[i] = tile[i % 80][i / 80];
  if (t < 80) {
    float s = 0.f;
    #pragma unroll
    for (int k = 0; k < 80; k++) { float v = b2f(tile[t][k]); s += v * v; }
    (ten ? rs_fy : rs_fx)[pl * 80 + t] = s;
  } else if (t < 160) {
    int w = t - 80; float s = 0.f;
    #pragma unroll
    for (int h = 0; h < 80; h++) { float v = b2f(tile[h][w]); s += v * v; }
    (ten ? cs_fy : cs_fx)[pl * 80 + w] = s;
  }
}

// ---- K5: combine over ci -> inverse norms ----
__global__ __launch_bounds__(256) void norm_combine(const float* __restrict__ rs_fx,
    const float* __restrict__ rs_fy, const float* __restrict__ cs_fx,
    const float* __restrict__ cs_fy, float* __restrict__ invn, int Nb)
{
  int t = blockIdx.x * 256 + threadIdx.x;   // 4*Nb*640 total
  int blk = Nb * 640;
  int side = t / blk, r = t % blk;
  int b = r / 640, rem = r % 640, hd = rem / 80, row = rem % 80;
  const float* src = (side == 0) ? rs_fy : (side == 1) ? rs_fx : (side == 2) ? cs_fx : cs_fy;
  size_t base = (size_t)(b * 256 + hd * 32) * 80 + row;
  float s = 0.f;
  #pragma unroll
  for (int ci = 0; ci < 32; ci++) s += src[base + ci * 80];
  invn[t] = 1.f / fmaxf(sqrtf(s), 1e-12f);
}

// ---- MFMA helpers for 80x80 Gram-style tiles ----
template<int T0, int NT>
__device__ __forceinline__ void gram_wave(const u16* pa, const u16* pb,
                                          int lg, int lr, f32x4* acc)
{
  constexpr int MLO = T0 / 5;
  #pragma unroll
  for (int ch = 0; ch < 3; ch++) {
    bool tz = (ch == 2) && (lg >= 2);
    int kk = ch * 32 + 8 * lg;
    if (tz) kk = 0;
    bf16x8 af[2], bf[5];
    #pragma unroll
    for (int m = 0; m < 2; m++)
      af[m] = *(const bf16x8*)(pa + ((MLO + m) * 16 + lr) * 80 + kk);
    #pragma unroll
    for (int n = 0; n < 5; n++)
      bf[n] = *(const bf16x8*)(pb + (n * 16 + lr) * 80 + kk);
    if (tz) {
      bf16x8 z = {0, 0, 0, 0, 0, 0, 0, 0};
      af[0] = z; af[1] = z;
    }
    #pragma unroll
    for (int j = 0; j < NT; j++) {
      acc[j] = __builtin_amdgcn_mfma_f32_16x16x32_bf16(
          af[(T0 + j) / 5 - MLO], bf[(T0 + j) % 5], acc[j], 0, 0, 0);
    }
  }
}

template<int T0, int NT>
__device__ __forceinline__ void gram_all(const u16* Ab, const u16* Bb,
                                         int lg, int lr, f32x4* acc)
{
  for (int ci = 0; ci < 32; ci++)
    gram_wave<T0, NT>(Ab + (size_t)ci * NHW, Bb + (size_t)ci * NHW, lg, lr, acc);
}

// ---- K6: MFMA Gram (sum over 32 ci) + cosine scale + softmax -> Sbuf ----
__global__ __launch_bounds__(256) void gram_softmax_mfma(const u16* __restrict__ fx,
    const u16* __restrict__ fy, const u16* __restrict__ fxT, const u16* __restrict__ fyT,
    const float* __restrict__ invn, u16* __restrict__ Sbuf, int Nb)
{
  __shared__ float At[80][81];
  int hd = blockIdx.x, b = blockIdx.y, axis = blockIdx.z;
  size_t sl0 = (size_t)(b * 256 + hd * 32) * NHW;
  const u16* Ab = (axis ? fxT : fy) + sl0;
  const u16* Bb = (axis ? fyT : fx) + sl0;
  int t = threadIdx.x, lane = t & 63, wid = t >> 6;
  int lg = lane >> 4, lr = lane & 15;
  f32x4 acc0 = {0.f, 0.f, 0.f, 0.f};
  f32x4 acc[7];
  #pragma unroll
  for (int j = 0; j < 7; j++) acc[j] = acc0;
  if      (wid == 0) gram_all<0, 7>(Ab, Bb, lg, lr, acc);
  else if (wid == 1) gram_all<7, 6>(Ab, Bb, lg, lr, acc);
  else if (wid == 2) gram_all<13, 6>(Ab, Bb, lg, lr, acc);
  else               gram_all<19, 6>(Ab, Bb, lg, lr, acc);
  int blk = Nb * 640;
  int rowbase = (b * 8 + hd) * 80;
  const float* invq = invn + (axis ? 2 * blk : 0)   + rowbase;
  const float* invk = invn + (axis ? 3 * blk : blk) + rowbase;
  int t0  = wid ? 6 * wid + 1 : 0;
  int cnt = wid ? 6 : 7;
  #pragma unroll
  for (int j = 0; j < 7; j++) {
    if (j < cnt) {
      int tt = t0 + j, m = tt / 5, n = tt % 5;
      int col = n * 16 + lr;
      float ik = invk[col];
      #pragma unroll
      for (int r = 0; r < 4; r++) {
        int row = m * 16 + 4 * lg + r;
        float gv = acc[j][r] * invq[row] * ik;
        At[row][col] = fminf(fmaxf(gv, -8.f), 8.f);  // |cos|<=1; NaN->-8
      }
    }
  }
  __syncthreads();
  u16* Sg = Sbuf + ((size_t)(axis * Nb * 8 + b * 8 + hd)) * NHW;
  if (t < 80) {
    float mx = -1e30f;
    for (int j = 0; j < 80; j++) mx = fmaxf(mx, At[t][j]);
    float s = 0.f;
    for (int j = 0; j < 80; j++) s += __expf(At[t][j] - mx);
    float inv = 1.f / s;
    for (int j = 0; j < 80; j++) Sg[t * 80 + j] = f2b(__expf(At[t][j] - mx) * inv);
  }
}

// ---- K7: MFMA fused H+W attention apply, IN PLACE over fx slice ----
template<int T0, int NT>
__device__ __forceinline__ void apply_wave(const u16* SH, const u16* fxT,
    const u16* fyP, const u16* SW, int lg, int lr, f32x4* acc)
{
  constexpr int MLO = T0 / 5;
  for (int ch = 0; ch < 3; ch++) {
    bool tz = (ch == 2) && (lg >= 2);
    int kk = ch * 32 + 8 * lg;
    if (tz) kk = 0;
    bf16x8 a1[2], a2[2], b1[5], b2[5];
    #pragma unroll
    for (int m = 0; m < 2; m++) {
      a1[m] = *(const bf16x8*)(SH  + ((MLO + m) * 16 + lr) * 80 + kk);
      a2[m] = *(const bf16x8*)(fyP + ((MLO + m) * 16 + lr) * 80 + kk);
    }
    #pragma unroll
    for (int n = 0; n < 5; n++) {
      b1[n] = *(const bf16x8*)(fxT + (n * 16 + lr) * 80 + kk);
      b2[n] = *(const bf16x8*)(SW  + (n * 16 + lr) * 80 + kk);
    }
    if (tz) {
      bf16x8 z = {0, 0, 0, 0, 0, 0, 0, 0};
      a1[0] = z; a1[1] = z; a2[0] = z; a2[1] = z;
    }
    #pragma unroll
    for (int j = 0; j < NT; j++) {
      acc[j] = __builtin_amdgcn_mfma_f32_16x16x32_bf16(
          a1[(T0 + j) / 5 - MLO], b1[(T0 + j) % 5], acc[j], 0, 0, 0);
      acc[j] = __builtin_amdgcn_mfma_f32_16x16x32_bf16(
          a2[(T0 + j) / 5 - MLO], b2[(T0 + j) % 5], acc[j], 0, 0, 0);
    }
  }
}

__global__ __launch_bounds__(256, 2) void apply_hw_mfma(const u16* __restrict__ fy_g,
    const u16* __restrict__ fxT_g, const u16* __restrict__ Sbuf,
    const float* __restrict__ invn, u16* fx_io, int Nb)
{
  int ci = blockIdx.x, hd = blockIdx.y, b = blockIdx.z;
  size_t off = (size_t)(b * 256 + hd * 32 + ci) * NHW;
  const u16* SgH = Sbuf + (size_t)(b * 8 + hd) * NHW;
  const u16* SgW = Sbuf + ((size_t)(Nb * 8) + b * 8 + hd) * NHW;
  const u16* fyP = fy_g + off;
  const u16* fxT = fxT_g + off;
  int t = threadIdx.x, lane = t & 63, wid = t >> 6;
  int lg = lane >> 4, lr = lane & 15;
  f32x4 acc0 = {0.f, 0.f, 0.f, 0.f};
  f32x4 acc[7];
  #pragma unroll
  for (int j = 0; j < 7; j++) acc[j] = acc0;
  if      (wid == 0) apply_wave<0, 7>(SgH, fxT, fyP, SgW, lg, lr, acc);
  else if (wid == 1) apply_wave<7, 6>(SgH, fxT, fyP, SgW, lg, lr, acc);
  else if (wid == 2) apply_wave<13, 6>(SgH, fxT, fyP, SgW, lg, lr, acc);
  else               apply_wave<19, 6>(SgH, fxT, fyP, SgW, lg, lr, acc);
  const float* invqH = invn + (b * 8 + hd) * 80;                 // H_fy(q)
  const float* invqW = invn + 2 * Nb * 640 + (b * 8 + hd) * 80;  // W_fx(q)
  int t0  = wid ? 6 * wid + 1 : 0;
  int cnt = wid ? 6 : 7;
  #pragma unroll
  for (int j = 0; j < 7; j++) {
    if (j < cnt) {
      int tt = t0 + j, m = tt / 5, n = tt % 5;
      int col = n * 16 + lr;
      float ivW = invqW[col];
      #pragma unroll
      for (int r = 0; r < 4; r++) {
        int row = m * 16 + 4 * lg + r;
        size_t ix = off + row * 80 + col;
        float v = acc[j][r] + b2f(fy_g[ix]) * invqH[row] + b2f(fx_io[ix]) * ivW;
        fx_io[ix] = f2b(v);
      }
    }
  }
}

extern "C" void kernel_launch(void* const* d_in, const int* in_sizes, int n_in,
                              void* d_out, int out_size, void* d_ws, size_t ws_size,
                              hipStream_t stream) {
  // Weight conversion table: d_in[1..18] in setup_inputs order.
  const int wsz[18] = {256, 256, 65536, 256, 65536, 256,
                       1792, 256, 2816, 256, 5376, 256,
                       1792, 256, 2816, 256, 5376, 256};
  CvtArgs ca;
  int cum = 0;
  for (int i = 0; i < 18; i++) { ca.src[i] = d_in[i + 1]; ca.cum[i] = cum; cum += wsz[i]; }
  ca.cum[18] = cum;   // 153600

  // Host-side dtype detection: x (and out) have 26,214,400 elements, so
  // 104857600 bytes => f32, 52428800 => bf16. Try in_sizes[0] AND out_size.
  // Fall back to the fast device probe only if neither matches.
  int hostf = -1;
  if (in_sizes && n_in > 0) {
    if      (in_sizes[0] == 104857600) hostf = 1;
    else if (in_sizes[0] == 52428800)  hostf = 0;
  }
  if (hostf < 0) {
    if      (out_size == 104857600) hostf = 1;
    else if (out_size == 52428800)  hostf = 0;
  }

  // ws layout: flag(16) | wbuf(614400) | wsplit(524288) | per-chunk buffers.
  int Nb = 1;
  for (int cand = 16; cand >= 1; cand >>= 1) {
    size_t need = (size_t)cand * 13701120 + 614416 + 524288;
    if (need <= ws_size) { Nb = cand; break; }
  }
  char* p = (char*)d_ws;
  int*    flag  = (int*)p;    p += 16;
  float*  wbuf  = (float*)p;  p += 614400;
  u16*    wsplit= (u16*)p;    p += 524288;     // [2 mat][2 set][256][256] bf16
  u16*    fxbuf = (u16*)p;    p += (size_t)Nb * 3276800;
  u16*    fybuf = (u16*)p;    p += (size_t)Nb * 3276800;
  u16*    fxT   = (u16*)p;    p += (size_t)Nb * 3276800;
  u16*    fyT   = (u16*)p;    p += (size_t)Nb * 3276800;
  float2* stats = (float2*)p; p += (size_t)Nb * 51200;
  float*  rs_fx = (float*)p;  p += (size_t)Nb * 81920;
  float*  rs_fy = (float*)p;  p += (size_t)Nb * 81920;
  float*  cs_fx = (float*)p;  p += (size_t)Nb * 81920;
  float*  cs_fy = (float*)p;  p += (size_t)Nb * 81920;
  float*  invn  = (float*)p;  p += (size_t)Nb * 10240;
  u16*    Sbuf  = (u16*)p;

  // f32 weight views
  float* ln_g = wbuf + ca.cum[0];  float* ln_b = wbuf + ca.cum[1];
  float* w_in = wbuf + ca.cum[2];  float* b_in = wbuf + ca.cum[3];
  float* w_out= wbuf + ca.cum[4]; float* b_out= wbuf + ca.cum[5];
  float* wx7  = wbuf + ca.cum[6];  float* bx7  = wbuf + ca.cum[7];
  float* wx11 = wbuf + ca.cum[8];  float* bx11 = wbuf + ca.cum[9];
  float* wx21 = wbuf + ca.cum[10]; float* bx21 = wbuf + ca.cum[11];
  float* wy7  = wbuf + ca.cum[12]; float* by7  = wbuf + ca.cum[13];
  float* wy11 = wbuf + ca.cum[14]; float* by11 = wbuf + ca.cum[15];
  float* wy21 = wbuf + ca.cum[16]; float* by21 = wbuf + ca.cum[17];

  if (hostf < 0) {
    probe_init<<<dim3(1), dim3(1), 0, stream>>>(flag);
    probe_count<<<dim3(64), dim3(256), 0, stream>>>((const u16*)d_in[0], flag);
    probe_decide<<<dim3(1), dim3(1), 0, stream>>>(flag);
  }
  cvt_weights<<<dim3(600), dim3(256), 0, stream>>>(ca, wbuf, hostf, flag);
  split_w<<<dim3(512), dim3(256), 0, stream>>>(w_in, w_out, wsplit);

  for (int b0 = 0; b0 < NB; b0 += Nb) {
    size_t xoff = (size_t)b0 * NC * NHW;   // element offset of chunk in x / out

    ln_stats<<<dim3(7, Nb), dim3(256), 0, stream>>>(d_in[0], xoff, hostf, flag, stats);
    dw_both<<<dim3(Nb * 256), dim3(256), 0, stream>>>(d_in[0], xoff, hostf, flag, stats,
        ln_g, ln_b, wx7, bx7, wx11, bx11, wx21, bx21,
        wy7, by7, wy11, by11, wy21, by21, fxbuf, fybuf);
    pw_mfma_t<0><<<dim3(100, Nb, 2), dim3(256), 0, stream>>>(wsplit, fxbuf, fybuf,
        b_in, nullptr, 0, nullptr, 0, hostf, flag);
    transpose_sumsq<<<dim3(Nb * 256, 2), dim3(256), 0, stream>>>(fxbuf, fybuf, fxT, fyT,
        rs_fx, rs_fy, cs_fx, cs_fy);
    norm_combine<<<dim3(10 * Nb), dim3(256), 0, stream>>>(rs_fx, rs_fy, cs_fx, cs_fy, invn, Nb);
    gram_softmax_mfma<<<dim3(8, Nb, 2), dim3(256), 0, stream>>>(fxbuf, fybuf, fxT, fyT, invn, Sbuf, Nb);
    apply_hw_mfma<<<dim3(32, 8, Nb), dim3(256), 0, stream>>>(fybuf, fxT, Sbuf, invn, fxbuf, Nb);
    pw_mfma_t<1><<<dim3(100, Nb, 1), dim3(256), 0, stream>>>(wsplit + 131072, fxbuf, nullptr,
        b_out, d_out, xoff, d_in[0], xoff, hostf, flag);
  }
  (void)in_sizes; (void)n_in; (void)out_size;
}